// Round 9
// baseline (590.358 us; speedup 1.0000x reference)
//
#include <hip/hip_runtime.h>
#include <math.h>

#define BB 16
#define NN 4096
#define SS 8
#define DD 64
#define DHH 128
#define CIN 66
#define NITERS 3
#define LN_EPS_F 1e-5f
#define EPS_ATTN_F 1e-8f
#define QSCALE 0.125f    // d^-0.5

__device__ __forceinline__ float dot4(float4 a, float4 b) {
    return fmaf(a.x, b.x, fmaf(a.y, b.y, fmaf(a.z, b.z, a.w * b.w)));
}

// ---------------------------------------------------------------- init slots
__global__ __launch_bounds__(256) void k_init_slots(
    const float* __restrict__ slots_in, float* __restrict__ slots,
    float* __restrict__ positions, float* __restrict__ scales) {
    int tid = blockIdx.x * 256 + threadIdx.x;
    if (tid < BB * SS * DD) {
        int s = (tid / DD) % SS;
        int c = tid % DD;
        slots[tid] = slots_in[s * 68 + c];
    }
    if (tid < BB * SS * 2) {
        int s = (tid >> 1) & 7;
        int p = tid & 1;
        float po = slots_in[s * 68 + 64 + p];
        positions[tid] = fminf(fmaxf(po, -1.f), 1.f);
        float sc = slots_in[s * 68 + 66 + p];
        scales[tid] = fminf(fmaxf(sc, 1e-3f), 2.f);
    }
}

// ---------------------------------------------------------------- prep W1-derived constants
__global__ __launch_bounds__(256) void k_prep_w(
    const float* __restrict__ W1, const float* __restrict__ lpg,
    const float* __restrict__ lpb, const float* __restrict__ b1,
    const float* __restrict__ Wg,
    float* __restrict__ W1p, float* __restrict__ avec, float* __restrict__ bvec,
    float* __restrict__ s1vec, float* __restrict__ b1p, float* __restrict__ wgc) {
    __shared__ float w1s[128 * 68];
    int tid = threadIdx.x;
    for (int q = 0; q < 8; q++) {
        int flat = q * 1024 + tid * 4;
        int o = flat >> 6, c = flat & 63;
        *(float4*)(w1s + o * 68 + c) = *(const float4*)(W1 + flat);
    }
    __syncthreads();
    if (tid < 128) {
        int o = tid;
        float a = 0.f, bv = 0.f, s1 = 0.f, b1a = b1[o];
        for (int c = 0; c < 64; c++) {
            float w0 = w1s[o * 68 + c];
            float w = w0 * lpg[c];
            W1p[o * 64 + c] = w;
            a = fmaf(w, Wg[2 * c], a);
            bv = fmaf(w, Wg[2 * c + 1], bv);
            s1 += w;
            b1a = fmaf(w0, lpb[c], b1a);
        }
        avec[o] = a; bvec[o] = bv; s1vec[o] = s1; b1p[o] = b1a;
    }
    if (tid == 128) {
        float mwA = 0.f, mwB = 0.f, AA = 0.f, BBv = 0.f, AB = 0.f;
        for (int c = 0; c < 64; c++) {
            float wa = Wg[2 * c], wb = Wg[2 * c + 1];
            mwA += wa; mwB += wb;
            AA = fmaf(wa, wa, AA); BBv = fmaf(wb, wb, BBv); AB = fmaf(wa, wb, AB);
        }
        wgc[0] = mwA * (1.f / 64.f);
        wgc[1] = mwB * (1.f / 64.f);
        wgc[2] = AA * (1.f / 64.f);
        wgc[3] = BBv * (1.f / 64.f);
        wgc[4] = AB * (2.f / 64.f);
    }
}

// ---------------------------------------------------------------- composite weights
__global__ __launch_bounds__(256) void k_prep_w2(
    const float* __restrict__ W1p, const float* __restrict__ Wk,
    const float* __restrict__ Wv, const float* __restrict__ bg,
    float* __restrict__ Wall, float* __restrict__ cu) {
    int flat = blockIdx.x * 256 + threadIdx.x;   // 64 blocks -> 16384
    int mat = flat >> 13, rem = flat & 8191;
    int o = rem >> 6, c = rem & 63;
    const float* Wm = mat ? Wv : Wk;
    float acc = 0.f;
    for (int d = 0; d < 64; d++)
        acc = fmaf(W1p[o * 64 + d], Wm[d * 64 + c], acc);
    Wall[flat] = acc;
    if (flat < 128) {
        float a = 0.f;
        for (int d = 0; d < 64; d++) a = fmaf(W1p[flat * 64 + d], bg[d], a);
        cu[flat] = a;
    }
}

// ---------------------------------------------------------------- main prep GEMM (round-7 exact)
// grid (1024, 3), 256 threads: chunk 0 -> uk, 1 -> uv, 2 -> moments
__global__ __launch_bounds__(256) void k_prep_main(
    const float* __restrict__ inp, const float* __restrict__ Wall,
    const float* __restrict__ cu, const float* __restrict__ Wk,
    const float* __restrict__ Wv, const float* __restrict__ bg,
    const float* __restrict__ Wg,
    float* __restrict__ uk, float* __restrict__ uv,
    float* __restrict__ kaux, float* __restrict__ vaux) {
    __shared__ float A[64 * 68];
    __shared__ float Bw[128 * 68];
    __shared__ float wg2[132];
    __shared__ float bgs[64];
    __shared__ float cus[128];
    int tid = threadIdx.x;
    int chunk = blockIdx.y;
    int rowBase = blockIdx.x * 64;
    {
        int r = tid >> 2, cq = (tid & 3) * 16;
        const float* src = inp + (size_t)(rowBase + r) * CIN + cq;
        float* dst = A + r * 68 + cq;
        #pragma unroll
        for (int q = 0; q < 8; q++) {
            float2 tv = *(const float2*)(src + 2 * q);
            dst[2 * q] = tv.x; dst[2 * q + 1] = tv.y;
        }
    }
    if (chunk < 2) {
        const float* Wsrc = Wall + (size_t)chunk * 8192;
        int o = tid >> 1, c0 = (tid & 1) * 32;
        #pragma unroll
        for (int q = 0; q < 8; q++)
            *(float4*)(Bw + o * 68 + c0 + 4 * q) = *(const float4*)(Wsrc + o * 64 + c0 + 4 * q);
        if (tid < 128) cus[tid] = cu[tid];
    } else {
        int o = tid >> 1, c0 = (tid & 1) * 32;
        const float* Wsrc = (o < 64) ? (Wk + o * 64) : (Wv + (o - 64) * 64);
        #pragma unroll
        for (int q = 0; q < 8; q++)
            *(float4*)(Bw + o * 68 + c0 + 4 * q) = *(const float4*)(Wsrc + c0 + 4 * q);
        if (tid < 64) {
            wg2[tid] = Wg[2 * tid]; wg2[66 + tid] = Wg[2 * tid + 1];
            bgs[tid] = bg[tid];
        }
    }
    __syncthreads();
    int r2 = tid >> 3, j = tid & 7;
    float acc0[16], acc1[16];
    #pragma unroll
    for (int q = 0; q < 16; q++) { acc0[q] = 0.f; acc1[q] = 0.f; }
    for (int c4 = 0; c4 < 64; c4 += 4) {
        float4 a0 = *(const float4*)(A + r2 * 68 + c4);
        float4 a1 = *(const float4*)(A + (r2 + 32) * 68 + c4);
        #pragma unroll
        for (int q = 0; q < 16; q++) {
            float4 w = *(const float4*)(Bw + (8 * q + j) * 68 + c4);
            acc0[q] += dot4(a0, w);
            acc1[q] += dot4(a1, w);
        }
    }
    if (chunk < 2) {
        float cub[16];
        #pragma unroll
        for (int q = 0; q < 16; q++) cub[q] = cus[8 * q + j];
        __syncthreads();
        #pragma unroll
        for (int q = 0; q < 16; q++) {
            Bw[r2 * 132 + 8 * q + j] = acc0[q] + cub[q];
            Bw[(r2 + 32) * 132 + 8 * q + j] = acc1[q] + cub[q];
        }
        __syncthreads();
        float* dst = (chunk == 0) ? uk : uv;
        int r = tid >> 2, c0 = (tid & 3) * 32;
        #pragma unroll
        for (int q = 0; q < 8; q++)
            *(float4*)(dst + (size_t)(rowBase + r) * 128 + c0 + 4 * q) =
                *(const float4*)(Bw + r * 132 + c0 + 4 * q);
    } else {
        float mk[2] = {0.f, 0.f}, kk[2] = {0.f, 0.f}, kA[2] = {0.f, 0.f}, kB[2] = {0.f, 0.f};
        float mv[2] = {0.f, 0.f}, vv[2] = {0.f, 0.f}, vA[2] = {0.f, 0.f}, vB[2] = {0.f, 0.f};
        #pragma unroll
        for (int q = 0; q < 8; q++) {
            int ch = 8 * q + j;
            float bgv = bgs[ch], wa = wg2[ch], wb = wg2[66 + ch];
            float x0 = acc0[q] + bgv, x1 = acc1[q] + bgv;
            mk[0] += x0; kk[0] = fmaf(x0, x0, kk[0]); kA[0] = fmaf(x0, wa, kA[0]); kB[0] = fmaf(x0, wb, kB[0]);
            mk[1] += x1; kk[1] = fmaf(x1, x1, kk[1]); kA[1] = fmaf(x1, wa, kA[1]); kB[1] = fmaf(x1, wb, kB[1]);
            float y0 = acc0[q + 8] + bgv, y1 = acc1[q + 8] + bgv;
            mv[0] += y0; vv[0] = fmaf(y0, y0, vv[0]); vA[0] = fmaf(y0, wa, vA[0]); vB[0] = fmaf(y0, wb, vB[0]);
            mv[1] += y1; vv[1] = fmaf(y1, y1, vv[1]); vA[1] = fmaf(y1, wa, vA[1]); vB[1] = fmaf(y1, wb, vB[1]);
        }
        #pragma unroll
        for (int off = 1; off <= 4; off <<= 1) {
            #pragma unroll
            for (int rr = 0; rr < 2; rr++) {
                mk[rr] += __shfl_xor(mk[rr], off, 64); kk[rr] += __shfl_xor(kk[rr], off, 64);
                kA[rr] += __shfl_xor(kA[rr], off, 64); kB[rr] += __shfl_xor(kB[rr], off, 64);
                mv[rr] += __shfl_xor(mv[rr], off, 64); vv[rr] += __shfl_xor(vv[rr], off, 64);
                vA[rr] += __shfl_xor(vA[rr], off, 64); vB[rr] += __shfl_xor(vB[rr], off, 64);
            }
        }
        if (j == 0) {
            #pragma unroll
            for (int rr = 0; rr < 2; rr++) {
                int row = rowBase + r2 + rr * 32;
                float g0 = inp[(size_t)row * CIN + 64];
                float g1 = inp[(size_t)row * CIN + 65];
                float4 m1 = {mk[rr] * (1.f / 64.f), kk[rr] * (1.f / 64.f),
                             kA[rr] * (1.f / 32.f), kB[rr] * (1.f / 32.f)};
                float4 m2 = {g0, g1, 0.f, 0.f};
                *(float4*)(kaux + (size_t)row * 8) = m1;
                *(float4*)(kaux + (size_t)row * 8 + 4) = m2;
                float4 n1 = {mv[rr] * (1.f / 64.f), vv[rr] * (1.f / 64.f),
                             vA[rr] * (1.f / 32.f), vB[rr] * (1.f / 32.f)};
                *(float4*)(vaux + (size_t)row * 8) = n1;
                *(float4*)(vaux + (size_t)row * 8 + 4) = m2;
            }
        }
    }
}

// ---------------------------------------------------------------- slot_prep (initial only)
__global__ __launch_bounds__(512) void k_slot_prep(
    const float* __restrict__ slots, const float* __restrict__ lsg,
    const float* __restrict__ lsb, const float* __restrict__ Wq,
    const float* __restrict__ W2, const float* __restrict__ b2,
    float* __restrict__ w2q, float* __restrict__ qb2) {
    __shared__ float sn[512];
    __shared__ float qv[SS][64];
    __shared__ float wsum[8], wsum2[8];
    int b = blockIdx.x, t = threadIdx.x;
    int s = t >> 6, c = t & 63;
    float x = slots[(b * SS + s) * DD + c];
    float sum = x;
    for (int off = 32; off; off >>= 1) sum += __shfl_xor(sum, off, 64);
    float m = sum * (1.f / 64.f);
    float dv = x - m;
    float vs = dv * dv;
    for (int off = 32; off; off >>= 1) vs += __shfl_xor(vs, off, 64);
    float y = dv * rsqrtf(vs * (1.f / 64.f) + LN_EPS_F) * lsg[c] + lsb[c];
    float s1 = y, s2 = y * y;
    for (int off = 32; off; off >>= 1) { s1 += __shfl_xor(s1, off, 64); s2 += __shfl_xor(s2, off, 64); }
    if (c == 0) { wsum[s] = s1; wsum2[s] = s2; }
    __syncthreads();
    float ts1 = 0.f, ts2 = 0.f;
    #pragma unroll
    for (int i = 0; i < 8; i++) { ts1 += wsum[i]; ts2 += wsum2[i]; }
    float gm = ts1 * (1.f / 512.f);
    float gv = ts2 * (1.f / 512.f) - gm * gm;
    sn[t] = (y - gm) * rsqrtf(gv + LN_EPS_F);
    __syncthreads();
    float acc = 0.f;
    for (int j4 = 0; j4 < 64; j4 += 4)
        acc += dot4(*(const float4*)&sn[s * 64 + j4], *(const float4*)(Wq + c * 64 + j4));
    qv[s][c] = acc;
    __syncthreads();
    float a0 = 0.f, a1 = 0.f;
    for (int cc = 0; cc < 64; cc++) {
        float qc = qv[s][cc];
        a0 = fmaf(qc, W2[cc * DHH + c], a0);
        a1 = fmaf(qc, W2[cc * DHH + c + 64], a1);
    }
    w2q[(b * SS + s) * DHH + c] = a0 * QSCALE;
    w2q[(b * SS + s) * DHH + c + 64] = a1 * QSCALE;
    float qb = qv[s][c] * b2[c];
    for (int off = 32; off; off >>= 1) qb += __shfl_xor(qb, off, 64);
    if (c == 0) qb2[b * SS + s] = qb * QSCALE;
}

// ---------------------------------------------------------------- pass1: dots (round-5 exact)
__global__ __launch_bounds__(256) void k_pass1(
    const float* __restrict__ uk, const float* __restrict__ kaux,
    const float* __restrict__ positions, const float* __restrict__ scales,
    const float* __restrict__ avec, const float* __restrict__ bvec,
    const float* __restrict__ s1vec, const float* __restrict__ b1p,
    const float* __restrict__ wgc, const float* __restrict__ w2q,
    const float* __restrict__ qb2, float* __restrict__ dots) {
    int tid = threadIdx.x;
    int chunk = blockIdx.x, b = blockIdx.y;
    int wv = tid >> 6, lane = tid & 63, rh = lane >> 5, ol = lane & 31;
    int o4 = ol * 4;
    float4 a4 = *(const float4*)(avec + o4);
    float4 bv4 = *(const float4*)(bvec + o4);
    float4 s14 = *(const float4*)(s1vec + o4);
    float4 b14 = *(const float4*)(b1p + o4);
    float mwA = wgc[0], mwB = wgc[1], AA = wgc[2], BBc = wgc[3], AB2 = wgc[4];
    float p0[8], p1[8], rc0[8], rc1[8], qb[8];
    float4 wq[8];
    #pragma unroll
    for (int s = 0; s < 8; s++) {
        int bs = b * 8 + s;
        p0[s] = positions[bs * 2]; p1[s] = positions[bs * 2 + 1];
        rc0[s] = 1.f / scales[bs * 2]; rc1[s] = 1.f / scales[bs * 2 + 1];
        qb[s] = qb2[bs];
        wq[s] = *(const float4*)(w2q + (size_t)bs * DHH + o4);
    }
    int row0 = chunk * 64 + wv * 16 + rh;
    size_t rg = (size_t)b * NN + row0;
    float4 m1 = *(const float4*)(kaux + rg * 8);
    float4 m2 = *(const float4*)(kaux + rg * 8 + 4);
    float4 u4 = *(const float4*)(uk + rg * 128 + o4);
    for (int st = 0; st < 8; st++) {
        float4 n1, n2, nu;
        if (st < 7) {
            size_t rgn = rg + (size_t)(st + 1) * 2;
            n1 = *(const float4*)(kaux + rgn * 8);
            n2 = *(const float4*)(kaux + rgn * 8 + 4);
            nu = *(const float4*)(uk + rgn * 128 + o4);
        }
        int row = row0 + st * 2;
        #pragma unroll
        for (int s = 0; s < 8; s++) {
            float rel0 = (m2.x - p0[s]) * rc0[s];
            float rel1 = (m2.y - p1[s]) * rc1[s];
            float m = fmaf(rel1, mwB, fmaf(rel0, mwA, m1.x));
            float q2 = fmaf(rel0, fmaf(rel0, AA, m1.z), m1.y);
            q2 = fmaf(rel1, fmaf(rel1, BBc, m1.w), q2);
            q2 = fmaf(rel0 * rel1, AB2, q2);
            float var = fmaf(-m, m, q2);
            float rstd = rsqrtf(fmaxf(var, 0.f) + LN_EPS_F);
            float p = 0.f, t, h;
            t = fmaf(-m, s14.x, u4.x); t = fmaf(rel0, a4.x, t); t = fmaf(rel1, bv4.x, t);
            h = fmaf(rstd, t, b14.x); p = fmaf(fmaxf(h, 0.f), wq[s].x, p);
            t = fmaf(-m, s14.y, u4.y); t = fmaf(rel0, a4.y, t); t = fmaf(rel1, bv4.y, t);
            h = fmaf(rstd, t, b14.y); p = fmaf(fmaxf(h, 0.f), wq[s].y, p);
            t = fmaf(-m, s14.z, u4.z); t = fmaf(rel0, a4.z, t); t = fmaf(rel1, bv4.z, t);
            h = fmaf(rstd, t, b14.z); p = fmaf(fmaxf(h, 0.f), wq[s].z, p);
            t = fmaf(-m, s14.w, u4.w); t = fmaf(rel0, a4.w, t); t = fmaf(rel1, bv4.w, t);
            h = fmaf(rstd, t, b14.w); p = fmaf(fmaxf(h, 0.f), wq[s].w, p);
            p += __shfl_xor(p, 1, 64);
            p += __shfl_xor(p, 2, 64);
            p += __shfl_xor(p, 4, 64);
            p += __shfl_xor(p, 8, 64);
            p += __shfl_xor(p, 16, 64);
            if (ol == 0)
                dots[(size_t)(b * 8 + s) * NN + row] = p + qb[s];
        }
        m1 = n1; m2 = n2; u4 = nu;
    }
}

// ---------------------------------------------------------------- pass2: H (round-5 exact)
__global__ __launch_bounds__(256) void k_pass2(
    const float* __restrict__ uv, const float* __restrict__ vaux,
    const float* __restrict__ positions, const float* __restrict__ scales,
    const float* __restrict__ avec, const float* __restrict__ bvec,
    const float* __restrict__ s1vec, const float* __restrict__ b1p,
    const float* __restrict__ wgc, const float* __restrict__ attn,
    float* __restrict__ H) {
    __shared__ float Hw[4 * 1024];
    int tid = threadIdx.x;
    int chunk = blockIdx.x, b = blockIdx.y;
    int wv = tid >> 6, lane = tid & 63, rh = lane >> 5, ol = lane & 31;
    int o4 = ol * 4;
    float4 a4 = *(const float4*)(avec + o4);
    float4 bv4 = *(const float4*)(bvec + o4);
    float4 s14 = *(const float4*)(s1vec + o4);
    float4 b14 = *(const float4*)(b1p + o4);
    float mwA = wgc[0], mwB = wgc[1], AA = wgc[2], BBc = wgc[3], AB2 = wgc[4];
    float p0[8], p1[8], rc0[8], rc1[8];
    #pragma unroll
    for (int s = 0; s < 8; s++) {
        int bs = b * 8 + s;
        p0[s] = positions[bs * 2]; p1[s] = positions[bs * 2 + 1];
        rc0[s] = 1.f / scales[bs * 2]; rc1[s] = 1.f / scales[bs * 2 + 1];
    }
    float hq[8][4];
    #pragma unroll
    for (int s = 0; s < 8; s++)
        #pragma unroll
        for (int c = 0; c < 4; c++) hq[s][c] = 0.f;
    int row0 = chunk * 64 + wv * 16 + rh;
    size_t rg = (size_t)b * NN + row0;
    float4 m1 = *(const float4*)(vaux + rg * 8);
    float4 m2 = *(const float4*)(vaux + rg * 8 + 4);
    float4 u4 = *(const float4*)(uv + rg * 128 + o4);
    for (int st = 0; st < 8; st++) {
        float4 n1, n2, nu;
        if (st < 7) {
            size_t rgn = rg + (size_t)(st + 1) * 2;
            n1 = *(const float4*)(vaux + rgn * 8);
            n2 = *(const float4*)(vaux + rgn * 8 + 4);
            nu = *(const float4*)(uv + rgn * 128 + o4);
        }
        int row = row0 + st * 2;
        #pragma unroll
        for (int s = 0; s < 8; s++) {
            float ar = attn[(size_t)(b * 8 + s) * NN + row];
            float rel0 = (m2.x - p0[s]) * rc0[s];
            float rel1 = (m2.y - p1[s]) * rc1[s];
            float m = fmaf(rel1, mwB, fmaf(rel0, mwA, m1.x));
            float q2 = fmaf(rel0, fmaf(rel0, AA, m1.z), m1.y);
            q2 = fmaf(rel1, fmaf(rel1, BBc, m1.w), q2);
            q2 = fmaf(rel0 * rel1, AB2, q2);
            float var = fmaf(-m, m, q2);
            float rstd = rsqrtf(fmaxf(var, 0.f) + LN_EPS_F);
            float t, h;
            t = fmaf(-m, s14.x, u4.x); t = fmaf(rel0, a4.x, t); t = fmaf(rel1, bv4.x, t);
            h = fmaf(rstd, t, b14.x); hq[s][0] = fmaf(ar, fmaxf(h, 0.f), hq[s][0]);
            t = fmaf(-m, s14.y, u4.y); t = fmaf(rel0, a4.y, t); t = fmaf(rel1, bv4.y, t);
            h = fmaf(rstd, t, b14.y); hq[s][1] = fmaf(ar, fmaxf(h, 0.f), hq[s][1]);
            t = fmaf(-m, s14.z, u4.z); t = fmaf(rel0, a4.z, t); t = fmaf(rel1, bv4.z, t);
            h = fmaf(rstd, t, b14.z); hq[s][2] = fmaf(ar, fmaxf(h, 0.f), hq[s][2]);
            t = fmaf(-m, s14.w, u4.w); t = fmaf(rel0, a4.w, t); t = fmaf(rel1, bv4.w, t);
            h = fmaf(rstd, t, b14.w); hq[s][3] = fmaf(ar, fmaxf(h, 0.f), hq[s][3]);
        }
        m1 = n1; m2 = n2; u4 = nu;
    }
    #pragma unroll
    for (int s = 0; s < 8; s++)
        #pragma unroll
        for (int c = 0; c < 4; c++)
            hq[s][c] += __shfl_xor(hq[s][c], 32, 64);
    if (lane < 32) {
        #pragma unroll
        for (int s = 0; s < 8; s++) {
            float4 st = {hq[s][0], hq[s][1], hq[s][2], hq[s][3]};
            *(float4*)(Hw + wv * 1024 + s * 128 + o4) = st;
        }
    }
    __syncthreads();
    #pragma unroll
    for (int q = 0; q < 4; q++) {
        int flat = q * 256 + tid;
        float sum = Hw[flat] + Hw[1024 + flat] + Hw[2048 + flat] + Hw[3072 + flat];
        atomicAdd(&H[(size_t)b * 8 * DHH + flat], sum);
    }
}

// ---------------------------------------------------------------- softmax M,L (+zero H, stats5)
__global__ __launch_bounds__(256) void k_softmax_ms(
    const float* __restrict__ dots, float* __restrict__ Mv, float* __restrict__ Lv,
    float* __restrict__ H, float* __restrict__ stats5) {
    __shared__ float red[4];
    int bs = blockIdx.x, t = threadIdx.x;
    if (t < 128) H[(size_t)bs * DHH + t] = 0.f;
    if (t < 5) stats5[bs * 5 + t] = 0.f;
    const float* dp = dots + (size_t)bs * NN;
    float mx = -1e30f;
    #pragma unroll
    for (int it = 0; it < 4; it++) {
        float4 d = *(const float4*)(dp + it * 1024 + t * 4);
        mx = fmaxf(mx, fmaxf(fmaxf(d.x, d.y), fmaxf(d.z, d.w)));
    }
    for (int off = 32; off; off >>= 1) mx = fmaxf(mx, __shfl_xor(mx, off, 64));
    if ((t & 63) == 0) red[t >> 6] = mx;
    __syncthreads();
    float M = fmaxf(fmaxf(red[0], red[1]), fmaxf(red[2], red[3]));
    __syncthreads();
    float sm = 0.f;
    #pragma unroll
    for (int it = 0; it < 4; it++) {
        float4 d = *(const float4*)(dp + it * 1024 + t * 4);
        sm += expf(d.x - M) + expf(d.y - M) + expf(d.z - M) + expf(d.w - M);
    }
    for (int off = 32; off; off >>= 1) sm += __shfl_xor(sm, off, 64);
    if ((t & 63) == 0) red[t >> 6] = sm;
    __syncthreads();
    if (t == 0) { Mv[bs] = M; Lv[bs] = red[0] + red[1] + red[2] + red[3]; }
}

// ---------------------------------------------------------------- attn normalize + stats
__global__ __launch_bounds__(256) void k_attn_stats(
    const float* __restrict__ dots, const float* __restrict__ Mv,
    const float* __restrict__ Lv, const float* __restrict__ kaux,
    float* __restrict__ attn, float* __restrict__ stats5) {
    __shared__ float stS[40];
    __shared__ float Ml[8], Rl[8];
    int chunk = blockIdx.x, b = blockIdx.y;
    int t = threadIdx.x;
    if (t < 8) { Ml[t] = Mv[b * 8 + t]; Rl[t] = 1.f / Lv[b * 8 + t]; }
    if (t >= 8 && t < 48) stS[t - 8] = 0.f;
    __syncthreads();
    int n = chunk * 256 + t;
    float a[8];
    float rs = 0.f;
    #pragma unroll
    for (int s = 0; s < 8; s++) {
        float d = dots[(size_t)(b * 8 + s) * NN + n];
        a[s] = expf(d - Ml[s]) * Rl[s] + EPS_ATTN_F;
        rs += a[s];
    }
    float inv = 1.f / rs;
    #pragma unroll
    for (int s = 0; s < 8; s++) {
        a[s] *= inv;
        attn[(size_t)(b * 8 + s) * NN + n] = a[s];
    }
    float2 g = *(const float2*)(kaux + ((size_t)b * NN + n) * 8 + 4);
    int lane = t & 63;
    #pragma unroll
    for (int s = 0; s < 8; s++) {
        float v0 = a[s];
        float v1 = a[s] * g.x, v2 = a[s] * g.y;
        float v3 = v1 * g.x, v4 = v2 * g.y;
        for (int off = 32; off; off >>= 1) {
            v0 += __shfl_xor(v0, off, 64); v1 += __shfl_xor(v1, off, 64);
            v2 += __shfl_xor(v2, off, 64); v3 += __shfl_xor(v3, off, 64);
            v4 += __shfl_xor(v4, off, 64);
        }
        if (lane == 0) {
            atomicAdd(&stS[s * 5 + 0], v0);
            atomicAdd(&stS[s * 5 + 1], v1);
            atomicAdd(&stS[s * 5 + 2], v2);
            atomicAdd(&stS[s * 5 + 3], v3);
            atomicAdd(&stS[s * 5 + 4], v4);
        }
    }
    __syncthreads();
    if (t < 40) atomicAdd(&stats5[b * 40 + t], stS[t]);
}

// ---------------------------------------------------------------- fused finalize + GRU + MLP + slot_prep
__global__ __launch_bounds__(512) void k_gru_fused(
    const float* __restrict__ H, const float* __restrict__ stats5,
    float* __restrict__ positions, float* __restrict__ scales,
    const float* __restrict__ W2, const float* __restrict__ b2,
    const float* __restrict__ W_ih, const float* __restrict__ W_hh,
    const float* __restrict__ b_ih, const float* __restrict__ b_hh,
    const float* __restrict__ lmg, const float* __restrict__ lmb,
    const float* __restrict__ W3, const float* __restrict__ b3,
    const float* __restrict__ W4, const float* __restrict__ b4,
    const float* __restrict__ lsg, const float* __restrict__ lsb,
    const float* __restrict__ Wq,
    float* __restrict__ slots, float* __restrict__ w2q, float* __restrict__ qb2) {
    __shared__ float hl[SS][DHH], ul[SS][DD], sl[SS][DD], yl[SS][DD], hml[SS][DHH];
    __shared__ float a0s[8];
    __shared__ float sn[512];
    __shared__ float qv[SS][64];
    __shared__ float wsum[8], wsum2[8];
    int b = blockIdx.x, t = threadIdx.x;
    int s = t >> 6, c = t & 63;
    int bs = b * SS + s;
    if (t < 8) {
        int bss = b * SS + t;
        float A0 = stats5[bss * 5 + 0];
        float A1x = stats5[bss * 5 + 1], A1y = stats5[bss * 5 + 2];
        float A2x = stats5[bss * 5 + 3], A2y = stats5[bss * 5 + 4];
        positions[bss * 2 + 0] = A1x;
        positions[bss * 2 + 1] = A1y;
        float sx = A2x - A1x * A1x * (2.f - A0);
        float sy = A2y - A1y * A1y * (2.f - A0);
        scales[bss * 2 + 0] = fminf(fmaxf(sqrtf(fmaxf(sx, 0.f)), 1e-3f), 2.f);
        scales[bss * 2 + 1] = fminf(fmaxf(sqrtf(fmaxf(sy, 0.f)), 1e-3f), 2.f);
        a0s[t] = A0;
    }
    hl[s][c] = H[(size_t)bs * DHH + c];
    hl[s][c + 64] = H[(size_t)bs * DHH + 64 + c];
    float hold = slots[bs * DD + c];
    sl[s][c] = hold;
    __syncthreads();
    float A0 = a0s[s];
    float u = A0 * b2[c];
    for (int o = 0; o < DHH; o += 4) {
        float4 w = *(const float4*)(W2 + c * DHH + o);
        u = fmaf(w.x, hl[s][o], fmaf(w.y, hl[s][o + 1], fmaf(w.z, hl[s][o + 2], fmaf(w.w, hl[s][o + 3], u))));
    }
    ul[s][c] = u;
    __syncthreads();
    float gir = b_ih[c], giz = b_ih[64 + c], gin = b_ih[128 + c];
    float ghr = b_hh[c], ghz = b_hh[64 + c], ghn = b_hh[128 + c];
    for (int k4 = 0; k4 < DD; k4 += 4) {
        float4 uu = *(const float4*)(&ul[s][k4]);
        float4 hh = *(const float4*)(&sl[s][k4]);
        gir += dot4(uu, *(const float4*)(W_ih + c * DD + k4));
        giz += dot4(uu, *(const float4*)(W_ih + (64 + c) * DD + k4));
        gin += dot4(uu, *(const float4*)(W_ih + (128 + c) * DD + k4));
        ghr += dot4(hh, *(const float4*)(W_hh + c * DD + k4));
        ghz += dot4(hh, *(const float4*)(W_hh + (64 + c) * DD + k4));
        ghn += dot4(hh, *(const float4*)(W_hh + (128 + c) * DD + k4));
    }
    float rg = 1.f / (1.f + expf(-(gir + ghr)));
    float zg = 1.f / (1.f + expf(-(giz + ghz)));
    float ng = tanhf(gin + rg * ghn);
    float snew = (1.f - zg) * ng + zg * hold;
    float sum = snew;
    for (int off = 32; off; off >>= 1) sum += __shfl_xor(sum, off, 64);
    float m = sum * (1.f / 64.f);
    float dv = snew - m;
    float vv = dv * dv;
    for (int off = 32; off; off >>= 1) vv += __shfl_xor(vv, off, 64);
    yl[s][c] = dv * rsqrtf(vv * (1.f / 64.f) + LN_EPS_F) * lmg[c] + lmb[c];
    __syncthreads();
    float h0 = b3[c], h1 = b3[64 + c];
    for (int k4 = 0; k4 < DD; k4 += 4) {
        float4 yy = *(const float4*)(&yl[s][k4]);
        h0 += dot4(yy, *(const float4*)(W3 + c * DD + k4));
        h1 += dot4(yy, *(const float4*)(W3 + (64 + c) * DD + k4));
    }
    hml[s][c] = fmaxf(h0, 0.f);
    hml[s][64 + c] = fmaxf(h1, 0.f);
    __syncthreads();
    float outv = b4[c];
    for (int o4 = 0; o4 < DHH; o4 += 4) {
        float4 hm4 = *(const float4*)(&hml[s][o4]);
        outv += dot4(hm4, *(const float4*)(W4 + c * DHH + o4));
    }
    slots[bs * DD + c] = outv;
    // ---- slot_prep for next iteration ----
    float x = outv;
    float sums = x;
    for (int off = 32; off; off >>= 1) sums += __shfl_xor(sums, off, 64);
    float ms = sums * (1.f / 64.f);
    float dvs = x - ms;
    float vss = dvs * dvs;
    for (int off = 32; off; off >>= 1) vss += __shfl_xor(vss, off, 64);
    float y = dvs * rsqrtf(vss * (1.f / 64.f) + LN_EPS_F) * lsg[c] + lsb[c];
    float s1 = y, s2 = y * y;
    for (int off = 32; off; off >>= 1) { s1 += __shfl_xor(s1, off, 64); s2 += __shfl_xor(s2, off, 64); }
    if (c == 0) { wsum[s] = s1; wsum2[s] = s2; }
    __syncthreads();
    float ts1 = 0.f, ts2 = 0.f;
    #pragma unroll
    for (int i = 0; i < 8; i++) { ts1 += wsum[i]; ts2 += wsum2[i]; }
    float gm = ts1 * (1.f / 512.f);
    float gv = ts2 * (1.f / 512.f) - gm * gm;
    sn[t] = (y - gm) * rsqrtf(gv + LN_EPS_F);
    __syncthreads();
    float acc = 0.f;
    for (int j4 = 0; j4 < 64; j4 += 4)
        acc += dot4(*(const float4*)&sn[s * 64 + j4], *(const float4*)(Wq + c * 64 + j4));
    qv[s][c] = acc;
    __syncthreads();
    float a0 = 0.f, a1 = 0.f;
    for (int cc = 0; cc < 64; cc++) {
        float qc = qv[s][cc];
        a0 = fmaf(qc, W2[cc * DHH + c], a0);
        a1 = fmaf(qc, W2[cc * DHH + c + 64], a1);
    }
    w2q[(size_t)bs * DHH + c] = a0 * QSCALE;
    w2q[(size_t)bs * DHH + c + 64] = a1 * QSCALE;
    float qb = qv[s][c] * b2[c];
    for (int off = 32; off; off >>= 1) qb += __shfl_xor(qb, off, 64);
    if (c == 0) qb2[bs] = qb * QSCALE;
}

// ---------------------------------------------------------------- write out (final pos/scales from stats5)
__global__ __launch_bounds__(256) void k_write_out(
    const float* __restrict__ slots, const float* __restrict__ stats5,
    float* __restrict__ out) {
    int tid = blockIdx.x * 256 + threadIdx.x;
    if (tid >= BB * SS * 68) return;
    int bs = tid / 68, c = tid % 68;
    float v;
    if (c < 64) {
        v = slots[bs * 64 + c];
    } else {
        float A0 = stats5[bs * 5 + 0];
        if (c < 66) {
            v = stats5[bs * 5 + 1 + (c - 64)];
        } else {
            int p = c - 66;
            float A1 = stats5[bs * 5 + 1 + p];
            float A2 = stats5[bs * 5 + 3 + p];
            float sx = A2 - A1 * A1 * (2.f - A0);
            v = fminf(fmaxf(sqrtf(fmaxf(sx, 0.f)), 1e-3f), 2.f);
        }
    }
    out[tid] = v;
}

// ---------------------------------------------------------------- launcher
extern "C" void kernel_launch(void* const* d_in, const int* in_sizes, int n_in,
                              void* d_out, int out_size, void* d_ws, size_t ws_size,
                              hipStream_t stream) {
    (void)in_sizes; (void)n_in; (void)out_size; (void)ws_size;
    const float* inp = (const float*)d_in[0];
    const float* slots_in = (const float*)d_in[1];
    const float* Wq = (const float*)d_in[2];
    const float* Wk = (const float*)d_in[3];
    const float* Wv = (const float*)d_in[4];
    const float* Wg = (const float*)d_in[5];
    const float* bg = (const float*)d_in[6];
    const float* lpg = (const float*)d_in[7];
    const float* lpb = (const float*)d_in[8];
    const float* W1 = (const float*)d_in[9];
    const float* b1 = (const float*)d_in[10];
    const float* W2 = (const float*)d_in[11];
    const float* b2 = (const float*)d_in[12];
    const float* W_ih = (const float*)d_in[13];
    const float* W_hh = (const float*)d_in[14];
    const float* b_ih = (const float*)d_in[15];
    const float* b_hh = (const float*)d_in[16];
    const float* lmg = (const float*)d_in[17];
    const float* lmb = (const float*)d_in[18];
    const float* W3 = (const float*)d_in[19];
    const float* b3 = (const float*)d_in[20];
    const float* W4 = (const float*)d_in[21];
    const float* b4 = (const float*)d_in[22];
    const float* lsg = (const float*)d_in[23];
    const float* lsb = (const float*)d_in[24];
    float* out = (float*)d_out;
    float* ws = (float*)d_ws;

    const size_t NR = (size_t)BB * NN;
    size_t o_uk = 0;
    size_t o_uv = o_uk + NR * 128;
    size_t o_kaux = o_uv + NR * 128;
    size_t o_vaux = o_kaux + NR * 8;
    size_t o_dots = o_vaux + NR * 8;
    size_t o_attn = o_dots + NR * SS;
    size_t o_slots = o_attn + NR * SS;
    size_t o_pos = o_slots + BB * SS * DD;
    size_t o_scl = o_pos + BB * SS * 2;
    size_t o_w2q = o_scl + BB * SS * 2;
    size_t o_qb2 = o_w2q + BB * SS * DHH;
    size_t o_Mv = o_qb2 + BB * SS;
    size_t o_Lv = o_Mv + BB * SS;
    size_t o_H = o_Lv + BB * SS;
    size_t o_st5 = o_H + BB * SS * DHH;
    size_t o_W1p = o_st5 + BB * SS * 5;
    size_t o_avec = o_W1p + DHH * DD;
    size_t o_bvec = o_avec + DHH;
    size_t o_s1v = o_bvec + DHH;
    size_t o_b1p = o_s1v + DHH;
    size_t o_wgc = o_b1p + DHH;
    size_t o_Wall = o_wgc + 8;
    size_t o_cu = o_Wall + 2 * DHH * DD;

    float* uk = ws + o_uk;
    float* uv = ws + o_uv;
    float* kaux = ws + o_kaux;
    float* vaux = ws + o_vaux;
    float* dots = ws + o_dots;
    float* attn = ws + o_attn;
    float* slots = ws + o_slots;
    float* positions = ws + o_pos;
    float* scales = ws + o_scl;
    float* w2q = ws + o_w2q;
    float* qb2 = ws + o_qb2;
    float* Mv = ws + o_Mv;
    float* Lv = ws + o_Lv;
    float* H = ws + o_H;
    float* stats5 = ws + o_st5;
    float* W1p = ws + o_W1p;
    float* avec = ws + o_avec;
    float* bvec = ws + o_bvec;
    float* s1v = ws + o_s1v;
    float* b1p = ws + o_b1p;
    float* wgc = ws + o_wgc;
    float* Wall = ws + o_Wall;
    float* cu = ws + o_cu;

    k_init_slots<<<32, 256, 0, stream>>>(slots_in, slots, positions, scales);
    k_prep_w<<<1, 256, 0, stream>>>(W1, lpg, lpb, b1, Wg, W1p, avec, bvec, s1v, b1p, wgc);
    k_prep_w2<<<64, 256, 0, stream>>>(W1p, Wk, Wv, bg, Wall, cu);
    k_prep_main<<<dim3(1024, 3), 256, 0, stream>>>(inp, Wall, cu, Wk, Wv, bg, Wg,
                                                   uk, uv, kaux, vaux);
    k_slot_prep<<<BB, 512, 0, stream>>>(slots, lsg, lsb, Wq, W2, b2, w2q, qb2);

    for (int it = 0; it <= NITERS; ++it) {
        k_pass1<<<dim3(64, BB), 256, 0, stream>>>(uk, kaux, positions, scales,
                                                  avec, bvec, s1v, b1p, wgc, w2q, qb2, dots);
        k_softmax_ms<<<BB * SS, 256, 0, stream>>>(dots, Mv, Lv, H, stats5);
        k_attn_stats<<<dim3(16, BB), 256, 0, stream>>>(dots, Mv, Lv, kaux, attn, stats5);
        if (it < NITERS) {
            k_pass2<<<dim3(64, BB), 256, 0, stream>>>(uv, vaux, positions, scales,
                                                      avec, bvec, s1v, b1p, wgc, attn, H);
            k_gru_fused<<<BB, 512, 0, stream>>>(H, stats5, positions, scales,
                                                W2, b2, W_ih, W_hh, b_ih, b_hh,
                                                lmg, lmb, W3, b3, W4, b4,
                                                lsg, lsb, Wq, slots, w2q, qb2);
        }
    }
    k_write_out<<<34, 256, 0, stream>>>(slots, stats5, out);
}

// Round 10
// 469.485 us; speedup vs baseline: 1.2575x; 1.2575x over previous
//
#include <hip/hip_runtime.h>
#include <math.h>

#define BB 16
#define NN 4096
#define SS 8
#define DD 64
#define DHH 128
#define CIN 66
#define NITERS 3
#define LN_EPS_F 1e-5f
#define EPS_ATTN_F 1e-8f
#define QSCALE 0.125f    // d^-0.5

__device__ __forceinline__ float dot4(float4 a, float4 b) {
    return fmaf(a.x, b.x, fmaf(a.y, b.y, fmaf(a.z, b.z, a.w * b.w)));
}

// ---------------------------------------------------------------- init slots
__global__ __launch_bounds__(256) void k_init_slots(
    const float* __restrict__ slots_in, float* __restrict__ slots,
    float* __restrict__ positions, float* __restrict__ scales) {
    int tid = blockIdx.x * 256 + threadIdx.x;
    if (tid < BB * SS * DD) {
        int s = (tid / DD) % SS;
        int c = tid % DD;
        slots[tid] = slots_in[s * 68 + c];
    }
    if (tid < BB * SS * 2) {
        int s = (tid >> 1) & 7;
        int p = tid & 1;
        float po = slots_in[s * 68 + 64 + p];
        positions[tid] = fminf(fmaxf(po, -1.f), 1.f);
        float sc = slots_in[s * 68 + 66 + p];
        scales[tid] = fminf(fmaxf(sc, 1e-3f), 2.f);
    }
}

// ---------------------------------------------------------------- prep W1-derived constants
__global__ __launch_bounds__(256) void k_prep_w(
    const float* __restrict__ W1, const float* __restrict__ lpg,
    const float* __restrict__ lpb, const float* __restrict__ b1,
    const float* __restrict__ Wg,
    float* __restrict__ W1p, float* __restrict__ avec, float* __restrict__ bvec,
    float* __restrict__ s1vec, float* __restrict__ b1p, float* __restrict__ wgc) {
    __shared__ float w1s[128 * 68];
    int tid = threadIdx.x;
    for (int q = 0; q < 8; q++) {
        int flat = q * 1024 + tid * 4;
        int o = flat >> 6, c = flat & 63;
        *(float4*)(w1s + o * 68 + c) = *(const float4*)(W1 + flat);
    }
    __syncthreads();
    if (tid < 128) {
        int o = tid;
        float a = 0.f, bv = 0.f, s1 = 0.f, b1a = b1[o];
        for (int c = 0; c < 64; c++) {
            float w0 = w1s[o * 68 + c];
            float w = w0 * lpg[c];
            W1p[o * 64 + c] = w;
            a = fmaf(w, Wg[2 * c], a);
            bv = fmaf(w, Wg[2 * c + 1], bv);
            s1 += w;
            b1a = fmaf(w0, lpb[c], b1a);
        }
        avec[o] = a; bvec[o] = bv; s1vec[o] = s1; b1p[o] = b1a;
    }
    if (tid == 128) {
        float mwA = 0.f, mwB = 0.f, AA = 0.f, BBv = 0.f, AB = 0.f;
        for (int c = 0; c < 64; c++) {
            float wa = Wg[2 * c], wb = Wg[2 * c + 1];
            mwA += wa; mwB += wb;
            AA = fmaf(wa, wa, AA); BBv = fmaf(wb, wb, BBv); AB = fmaf(wa, wb, AB);
        }
        wgc[0] = mwA * (1.f / 64.f);
        wgc[1] = mwB * (1.f / 64.f);
        wgc[2] = AA * (1.f / 64.f);
        wgc[3] = BBv * (1.f / 64.f);
        wgc[4] = AB * (2.f / 64.f);
    }
}

// ---------------------------------------------------------------- composite weights
__global__ __launch_bounds__(256) void k_prep_w2(
    const float* __restrict__ W1p, const float* __restrict__ Wk,
    const float* __restrict__ Wv, const float* __restrict__ bg,
    float* __restrict__ Wall, float* __restrict__ cu) {
    int flat = blockIdx.x * 256 + threadIdx.x;   // 64 blocks -> 16384
    int mat = flat >> 13, rem = flat & 8191;
    int o = rem >> 6, c = rem & 63;
    const float* Wm = mat ? Wv : Wk;
    float acc = 0.f;
    for (int d = 0; d < 64; d++)
        acc = fmaf(W1p[o * 64 + d], Wm[d * 64 + c], acc);
    Wall[flat] = acc;
    if (flat < 128) {
        float a = 0.f;
        for (int d = 0; d < 64; d++) a = fmaf(W1p[flat * 64 + d], bg[d], a);
        cu[flat] = a;
    }
}

// ---------------------------------------------------------------- main prep GEMM (4 rows x 8 outs tile)
// grid (1024, 3), 256 threads, 64 rows/block: chunk 0 -> uk, 1 -> uv, 2 -> moments
__global__ __launch_bounds__(256) void k_prep_main(
    const float* __restrict__ inp, const float* __restrict__ Wall,
    const float* __restrict__ cu, const float* __restrict__ Wk,
    const float* __restrict__ Wv, const float* __restrict__ bg,
    const float* __restrict__ Wg,
    float* __restrict__ uk, float* __restrict__ uv,
    float* __restrict__ kaux, float* __restrict__ vaux, float* __restrict__ gbuf) {
    __shared__ float A[64 * 68];
    __shared__ float Bw[128 * 68];
    __shared__ float wg2[132];
    __shared__ float bgs[64];
    __shared__ float cus[128];
    int tid = threadIdx.x;
    int chunk = blockIdx.y;
    int rowBase = blockIdx.x * 64;
    {
        int r = tid >> 2, cq = (tid & 3) * 16;
        const float* src = inp + (size_t)(rowBase + r) * CIN + cq;
        float* dst = A + r * 68 + cq;
        #pragma unroll
        for (int q = 0; q < 8; q++) {
            float2 tv = *(const float2*)(src + 2 * q);
            dst[2 * q] = tv.x; dst[2 * q + 1] = tv.y;
        }
    }
    if (chunk < 2) {
        const float* Wsrc = Wall + (size_t)chunk * 8192;
        int o = tid >> 1, c0 = (tid & 1) * 32;
        #pragma unroll
        for (int q = 0; q < 8; q++)
            *(float4*)(Bw + o * 68 + c0 + 4 * q) = *(const float4*)(Wsrc + o * 64 + c0 + 4 * q);
        if (tid < 128) cus[tid] = cu[tid];
    } else {
        int o = tid >> 1, c0 = (tid & 1) * 32;
        const float* Wsrc = (o < 64) ? (Wk + o * 64) : (Wv + (o - 64) * 64);
        #pragma unroll
        for (int q = 0; q < 8; q++)
            *(float4*)(Bw + o * 68 + c0 + 4 * q) = *(const float4*)(Wsrc + c0 + 4 * q);
        if (tid < 64) {
            wg2[tid] = Wg[2 * tid]; wg2[66 + tid] = Wg[2 * tid + 1];
            bgs[tid] = bg[tid];
        }
    }
    __syncthreads();
    int r4 = tid >> 4, j = tid & 15;     // rows {r4+16rr}, outs {16q+j}
    float acc[4][8];
    #pragma unroll
    for (int rr = 0; rr < 4; rr++)
        #pragma unroll
        for (int q = 0; q < 8; q++) acc[rr][q] = 0.f;
    for (int c4 = 0; c4 < 64; c4 += 4) {
        float4 av[4];
        #pragma unroll
        for (int rr = 0; rr < 4; rr++)
            av[rr] = *(const float4*)(A + (r4 + 16 * rr) * 68 + c4);
        #pragma unroll
        for (int q = 0; q < 8; q++) {
            float4 w = *(const float4*)(Bw + (16 * q + j) * 68 + c4);
            #pragma unroll
            for (int rr = 0; rr < 4; rr++) acc[rr][q] += dot4(av[rr], w);
        }
    }
    if (chunk < 2) {
        float cub[8];
        #pragma unroll
        for (int q = 0; q < 8; q++) cub[q] = cus[16 * q + j];
        __syncthreads();
        #pragma unroll
        for (int rr = 0; rr < 4; rr++)
            #pragma unroll
            for (int q = 0; q < 8; q++)
                Bw[(r4 + 16 * rr) * 132 + 16 * q + j] = acc[rr][q] + cub[q];
        __syncthreads();
        float* dst = (chunk == 0) ? uk : uv;
        int r = tid >> 2, c0 = (tid & 3) * 32;
        #pragma unroll
        for (int q = 0; q < 8; q++)
            *(float4*)(dst + (size_t)(rowBase + r) * 128 + c0 + 4 * q) =
                *(const float4*)(Bw + r * 132 + c0 + 4 * q);
    } else {
        float wa[4], wb[4], bgk[4];
        #pragma unroll
        for (int q = 0; q < 4; q++) {
            int ch = 16 * q + j;
            wa[q] = wg2[ch]; wb[q] = wg2[66 + ch]; bgk[q] = bgs[ch];
        }
        #pragma unroll
        for (int rr = 0; rr < 4; rr++) {
            float mk = 0.f, kk = 0.f, kA = 0.f, kB = 0.f;
            float mv = 0.f, vv = 0.f, vA = 0.f, vB = 0.f;
            #pragma unroll
            for (int q = 0; q < 4; q++) {
                float x = acc[rr][q] + bgk[q];
                mk += x; kk = fmaf(x, x, kk); kA = fmaf(x, wa[q], kA); kB = fmaf(x, wb[q], kB);
                float y = acc[rr][q + 4] + bgk[q];
                mv += y; vv = fmaf(y, y, vv); vA = fmaf(y, wa[q], vA); vB = fmaf(y, wb[q], vB);
            }
            #pragma unroll
            for (int off = 1; off <= 8; off <<= 1) {
                mk += __shfl_xor(mk, off, 64); kk += __shfl_xor(kk, off, 64);
                kA += __shfl_xor(kA, off, 64); kB += __shfl_xor(kB, off, 64);
                mv += __shfl_xor(mv, off, 64); vv += __shfl_xor(vv, off, 64);
                vA += __shfl_xor(vA, off, 64); vB += __shfl_xor(vB, off, 64);
            }
            if (j == 0) {
                int row = rowBase + r4 + 16 * rr;
                float g0 = inp[(size_t)row * CIN + 64];
                float g1 = inp[(size_t)row * CIN + 65];
                float4 m1 = {mk * (1.f / 64.f), kk * (1.f / 64.f),
                             kA * (1.f / 32.f), kB * (1.f / 32.f)};
                float4 m2 = {g0, g1, 0.f, 0.f};
                *(float4*)(kaux + (size_t)row * 8) = m1;
                *(float4*)(kaux + (size_t)row * 8 + 4) = m2;
                float4 n1 = {mv * (1.f / 64.f), vv * (1.f / 64.f),
                             vA * (1.f / 32.f), vB * (1.f / 32.f)};
                *(float4*)(vaux + (size_t)row * 8) = n1;
                *(float4*)(vaux + (size_t)row * 8 + 4) = m2;
                float2 gw = {g0, g1};
                *(float2*)(gbuf + (size_t)row * 2) = gw;
            }
        }
    }
}

// ---------------------------------------------------------------- slot_prep: w2q, qb2
__global__ __launch_bounds__(512) void k_slot_prep(
    const float* __restrict__ slots, const float* __restrict__ lsg,
    const float* __restrict__ lsb, const float* __restrict__ Wq,
    const float* __restrict__ W2, const float* __restrict__ b2,
    float* __restrict__ w2q, float* __restrict__ qb2) {
    __shared__ float sn[512];
    __shared__ float qv[SS][64];
    __shared__ float wsum[8], wsum2[8];
    int b = blockIdx.x, t = threadIdx.x;
    int s = t >> 6, c = t & 63;
    float x = slots[(b * SS + s) * DD + c];
    float sum = x;
    for (int off = 32; off; off >>= 1) sum += __shfl_xor(sum, off, 64);
    float m = sum * (1.f / 64.f);
    float dv = x - m;
    float vs = dv * dv;
    for (int off = 32; off; off >>= 1) vs += __shfl_xor(vs, off, 64);
    float y = dv * rsqrtf(vs * (1.f / 64.f) + LN_EPS_F) * lsg[c] + lsb[c];
    float s1 = y, s2 = y * y;
    for (int off = 32; off; off >>= 1) { s1 += __shfl_xor(s1, off, 64); s2 += __shfl_xor(s2, off, 64); }
    if (c == 0) { wsum[s] = s1; wsum2[s] = s2; }
    __syncthreads();
    float ts1 = 0.f, ts2 = 0.f;
    #pragma unroll
    for (int i = 0; i < 8; i++) { ts1 += wsum[i]; ts2 += wsum2[i]; }
    float gm = ts1 * (1.f / 512.f);
    float gv = ts2 * (1.f / 512.f) - gm * gm;
    sn[t] = (y - gm) * rsqrtf(gv + LN_EPS_F);
    __syncthreads();
    float acc = 0.f;
    for (int j4 = 0; j4 < 64; j4 += 4)
        acc += dot4(*(const float4*)&sn[s * 64 + j4], *(const float4*)(Wq + c * 64 + j4));
    qv[s][c] = acc;
    __syncthreads();
    float a0 = 0.f, a1 = 0.f;
    for (int cc = 0; cc < 64; cc++) {
        float qc = qv[s][cc];
        a0 = fmaf(qc, W2[cc * DHH + c], a0);
        a1 = fmaf(qc, W2[cc * DHH + c + 64], a1);
    }
    w2q[(b * SS + s) * DHH + c] = a0 * QSCALE;
    w2q[(b * SS + s) * DHH + c + 64] = a1 * QSCALE;
    float qb = qv[s][c] * b2[c];
    for (int off = 32; off; off >>= 1) qb += __shfl_xor(qb, off, 64);
    if (c == 0) qb2[b * SS + s] = qb * QSCALE;
}

// ---------------------------------------------------------------- pass1: dots (round-5)
__global__ __launch_bounds__(256) void k_pass1(
    const float* __restrict__ uk, const float* __restrict__ kaux,
    const float* __restrict__ positions, const float* __restrict__ scales,
    const float* __restrict__ avec, const float* __restrict__ bvec,
    const float* __restrict__ s1vec, const float* __restrict__ b1p,
    const float* __restrict__ wgc, const float* __restrict__ w2q,
    const float* __restrict__ qb2, float* __restrict__ dots) {
    int tid = threadIdx.x;
    int chunk = blockIdx.x, b = blockIdx.y;
    int wv = tid >> 6, lane = tid & 63, rh = lane >> 5, ol = lane & 31;
    int o4 = ol * 4;
    float4 a4 = *(const float4*)(avec + o4);
    float4 bv4 = *(const float4*)(bvec + o4);
    float4 s14 = *(const float4*)(s1vec + o4);
    float4 b14 = *(const float4*)(b1p + o4);
    float mwA = wgc[0], mwB = wgc[1], AA = wgc[2], BBc = wgc[3], AB2 = wgc[4];
    float p0[8], p1[8], rc0[8], rc1[8], qb[8];
    float4 wq[8];
    #pragma unroll
    for (int s = 0; s < 8; s++) {
        int bs = b * 8 + s;
        p0[s] = positions[bs * 2]; p1[s] = positions[bs * 2 + 1];
        rc0[s] = 1.f / scales[bs * 2]; rc1[s] = 1.f / scales[bs * 2 + 1];
        qb[s] = qb2[bs];
        wq[s] = *(const float4*)(w2q + (size_t)bs * DHH + o4);
    }
    int row0 = chunk * 64 + wv * 16 + rh;
    size_t rg = (size_t)b * NN + row0;
    float4 m1 = *(const float4*)(kaux + rg * 8);
    float4 m2 = *(const float4*)(kaux + rg * 8 + 4);
    float4 u4 = *(const float4*)(uk + rg * 128 + o4);
    for (int st = 0; st < 8; st++) {
        float4 n1, n2, nu;
        if (st < 7) {
            size_t rgn = rg + (size_t)(st + 1) * 2;
            n1 = *(const float4*)(kaux + rgn * 8);
            n2 = *(const float4*)(kaux + rgn * 8 + 4);
            nu = *(const float4*)(uk + rgn * 128 + o4);
        }
        int row = row0 + st * 2;
        #pragma unroll
        for (int s = 0; s < 8; s++) {
            float rel0 = (m2.x - p0[s]) * rc0[s];
            float rel1 = (m2.y - p1[s]) * rc1[s];
            float m = fmaf(rel1, mwB, fmaf(rel0, mwA, m1.x));
            float q2 = fmaf(rel0, fmaf(rel0, AA, m1.z), m1.y);
            q2 = fmaf(rel1, fmaf(rel1, BBc, m1.w), q2);
            q2 = fmaf(rel0 * rel1, AB2, q2);
            float var = fmaf(-m, m, q2);
            float rstd = rsqrtf(fmaxf(var, 0.f) + LN_EPS_F);
            float p = 0.f, t, h;
            t = fmaf(-m, s14.x, u4.x); t = fmaf(rel0, a4.x, t); t = fmaf(rel1, bv4.x, t);
            h = fmaf(rstd, t, b14.x); p = fmaf(fmaxf(h, 0.f), wq[s].x, p);
            t = fmaf(-m, s14.y, u4.y); t = fmaf(rel0, a4.y, t); t = fmaf(rel1, bv4.y, t);
            h = fmaf(rstd, t, b14.y); p = fmaf(fmaxf(h, 0.f), wq[s].y, p);
            t = fmaf(-m, s14.z, u4.z); t = fmaf(rel0, a4.z, t); t = fmaf(rel1, bv4.z, t);
            h = fmaf(rstd, t, b14.z); p = fmaf(fmaxf(h, 0.f), wq[s].z, p);
            t = fmaf(-m, s14.w, u4.w); t = fmaf(rel0, a4.w, t); t = fmaf(rel1, bv4.w, t);
            h = fmaf(rstd, t, b14.w); p = fmaf(fmaxf(h, 0.f), wq[s].w, p);
            p += __shfl_xor(p, 1, 64);
            p += __shfl_xor(p, 2, 64);
            p += __shfl_xor(p, 4, 64);
            p += __shfl_xor(p, 8, 64);
            p += __shfl_xor(p, 16, 64);
            if (ol == 0)
                dots[(size_t)(b * 8 + s) * NN + row] = p + qb[s];
        }
        m1 = n1; m2 = n2; u4 = nu;
    }
}

// ---------------------------------------------------------------- pass2: H (round-5)
__global__ __launch_bounds__(256) void k_pass2(
    const float* __restrict__ uv, const float* __restrict__ vaux,
    const float* __restrict__ positions, const float* __restrict__ scales,
    const float* __restrict__ avec, const float* __restrict__ bvec,
    const float* __restrict__ s1vec, const float* __restrict__ b1p,
    const float* __restrict__ wgc, const float* __restrict__ attn,
    float* __restrict__ H) {
    __shared__ float Hw[4 * 1024];
    int tid = threadIdx.x;
    int chunk = blockIdx.x, b = blockIdx.y;
    int wv = tid >> 6, lane = tid & 63, rh = lane >> 5, ol = lane & 31;
    int o4 = ol * 4;
    float4 a4 = *(const float4*)(avec + o4);
    float4 bv4 = *(const float4*)(bvec + o4);
    float4 s14 = *(const float4*)(s1vec + o4);
    float4 b14 = *(const float4*)(b1p + o4);
    float mwA = wgc[0], mwB = wgc[1], AA = wgc[2], BBc = wgc[3], AB2 = wgc[4];
    float p0[8], p1[8], rc0[8], rc1[8];
    #pragma unroll
    for (int s = 0; s < 8; s++) {
        int bs = b * 8 + s;
        p0[s] = positions[bs * 2]; p1[s] = positions[bs * 2 + 1];
        rc0[s] = 1.f / scales[bs * 2]; rc1[s] = 1.f / scales[bs * 2 + 1];
    }
    float hq[8][4];
    #pragma unroll
    for (int s = 0; s < 8; s++)
        #pragma unroll
        for (int c = 0; c < 4; c++) hq[s][c] = 0.f;
    int row0 = chunk * 64 + wv * 16 + rh;
    size_t rg = (size_t)b * NN + row0;
    float4 m1 = *(const float4*)(vaux + rg * 8);
    float4 m2 = *(const float4*)(vaux + rg * 8 + 4);
    float4 u4 = *(const float4*)(uv + rg * 128 + o4);
    for (int st = 0; st < 8; st++) {
        float4 n1, n2, nu;
        if (st < 7) {
            size_t rgn = rg + (size_t)(st + 1) * 2;
            n1 = *(const float4*)(vaux + rgn * 8);
            n2 = *(const float4*)(vaux + rgn * 8 + 4);
            nu = *(const float4*)(uv + rgn * 128 + o4);
        }
        int row = row0 + st * 2;
        #pragma unroll
        for (int s = 0; s < 8; s++) {
            float ar = attn[(size_t)(b * 8 + s) * NN + row];
            float rel0 = (m2.x - p0[s]) * rc0[s];
            float rel1 = (m2.y - p1[s]) * rc1[s];
            float m = fmaf(rel1, mwB, fmaf(rel0, mwA, m1.x));
            float q2 = fmaf(rel0, fmaf(rel0, AA, m1.z), m1.y);
            q2 = fmaf(rel1, fmaf(rel1, BBc, m1.w), q2);
            q2 = fmaf(rel0 * rel1, AB2, q2);
            float var = fmaf(-m, m, q2);
            float rstd = rsqrtf(fmaxf(var, 0.f) + LN_EPS_F);
            float t, h;
            t = fmaf(-m, s14.x, u4.x); t = fmaf(rel0, a4.x, t); t = fmaf(rel1, bv4.x, t);
            h = fmaf(rstd, t, b14.x); hq[s][0] = fmaf(ar, fmaxf(h, 0.f), hq[s][0]);
            t = fmaf(-m, s14.y, u4.y); t = fmaf(rel0, a4.y, t); t = fmaf(rel1, bv4.y, t);
            h = fmaf(rstd, t, b14.y); hq[s][1] = fmaf(ar, fmaxf(h, 0.f), hq[s][1]);
            t = fmaf(-m, s14.z, u4.z); t = fmaf(rel0, a4.z, t); t = fmaf(rel1, bv4.z, t);
            h = fmaf(rstd, t, b14.z); hq[s][2] = fmaf(ar, fmaxf(h, 0.f), hq[s][2]);
            t = fmaf(-m, s14.w, u4.w); t = fmaf(rel0, a4.w, t); t = fmaf(rel1, bv4.w, t);
            h = fmaf(rstd, t, b14.w); hq[s][3] = fmaf(ar, fmaxf(h, 0.f), hq[s][3]);
        }
        m1 = n1; m2 = n2; u4 = nu;
    }
    #pragma unroll
    for (int s = 0; s < 8; s++)
        #pragma unroll
        for (int c = 0; c < 4; c++)
            hq[s][c] += __shfl_xor(hq[s][c], 32, 64);
    if (lane < 32) {
        #pragma unroll
        for (int s = 0; s < 8; s++) {
            float4 st = {hq[s][0], hq[s][1], hq[s][2], hq[s][3]};
            *(float4*)(Hw + wv * 1024 + s * 128 + o4) = st;
        }
    }
    __syncthreads();
    #pragma unroll
    for (int q = 0; q < 4; q++) {
        int flat = q * 256 + tid;
        float sum = Hw[flat] + Hw[1024 + flat] + Hw[2048 + flat] + Hw[3072 + flat];
        atomicAdd(&H[(size_t)b * 8 * DHH + flat], sum);
    }
}

// ---------------------------------------------------------------- softmax M,L (+zero H)
__global__ __launch_bounds__(256) void k_softmax_ms(
    const float* __restrict__ dots, float* __restrict__ Mv, float* __restrict__ Lv,
    float* __restrict__ H) {
    __shared__ float red[4];
    int bs = blockIdx.x, t = threadIdx.x;
    if (t < 128) H[(size_t)bs * DHH + t] = 0.f;
    const float* dp = dots + (size_t)bs * NN;
    float mx = -1e30f;
    #pragma unroll
    for (int it = 0; it < 4; it++) {
        float4 d = *(const float4*)(dp + it * 1024 + t * 4);
        mx = fmaxf(mx, fmaxf(fmaxf(d.x, d.y), fmaxf(d.z, d.w)));
    }
    for (int off = 32; off; off >>= 1) mx = fmaxf(mx, __shfl_xor(mx, off, 64));
    if ((t & 63) == 0) red[t >> 6] = mx;
    __syncthreads();
    float M = fmaxf(fmaxf(red[0], red[1]), fmaxf(red[2], red[3]));
    __syncthreads();
    float sm = 0.f;
    #pragma unroll
    for (int it = 0; it < 4; it++) {
        float4 d = *(const float4*)(dp + it * 1024 + t * 4);
        sm += expf(d.x - M) + expf(d.y - M) + expf(d.z - M) + expf(d.w - M);
    }
    for (int off = 32; off; off >>= 1) sm += __shfl_xor(sm, off, 64);
    if ((t & 63) == 0) red[t >> 6] = sm;
    __syncthreads();
    if (t == 0) { Mv[bs] = M; Lv[bs] = red[0] + red[1] + red[2] + red[3]; }
}

// ---------------------------------------------------------------- attn normalize
__global__ __launch_bounds__(256) void k_attn(
    const float* __restrict__ dots, const float* __restrict__ Mv,
    const float* __restrict__ Lv, float* __restrict__ attn) {
    int chunk = blockIdx.x, b = blockIdx.y;
    int n = chunk * 256 + threadIdx.x;
    float a[8];
    float rs = 0.f;
    #pragma unroll
    for (int s = 0; s < 8; s++) {
        int bs = b * 8 + s;
        float d = dots[(size_t)bs * NN + n];
        a[s] = expf(d - Mv[bs]) * (1.f / Lv[bs]) + EPS_ATTN_F;
        rs += a[s];
    }
    float inv = 1.f / rs;
    #pragma unroll
    for (int s = 0; s < 8; s++)
        attn[(size_t)(b * 8 + s) * NN + n] = a[s] * inv;
}

// ---------------------------------------------------------------- stats + finalize
__global__ __launch_bounds__(256) void k_stats(
    const float* __restrict__ attn, const float* __restrict__ gbuf,
    float* __restrict__ positions, float* __restrict__ scales,
    float* __restrict__ stats) {
    __shared__ float red[4][5];
    int bs = blockIdx.x, b = bs >> 3, t = threadIdx.x;
    const float* ap = attn + (size_t)bs * NN;
    const float* gb = gbuf + (size_t)b * NN * 2;
    float v0 = 0.f, v1 = 0.f, v2 = 0.f, v3 = 0.f, v4 = 0.f;
    #pragma unroll
    for (int it = 0; it < 4; it++) {
        int n0 = it * 1024 + t * 4;
        float4 av = *(const float4*)(ap + n0);
        float4 g1 = *(const float4*)(gb + (size_t)n0 * 2);
        float4 g2 = *(const float4*)(gb + (size_t)n0 * 2 + 4);
        v0 += av.x + av.y + av.z + av.w;
        v1 = fmaf(av.x, g1.x, fmaf(av.y, g1.z, fmaf(av.z, g2.x, fmaf(av.w, g2.z, v1))));
        v2 = fmaf(av.x, g1.y, fmaf(av.y, g1.w, fmaf(av.z, g2.y, fmaf(av.w, g2.w, v2))));
        v3 = fmaf(av.x, g1.x * g1.x, fmaf(av.y, g1.z * g1.z, fmaf(av.z, g2.x * g2.x, fmaf(av.w, g2.z * g2.z, v3))));
        v4 = fmaf(av.x, g1.y * g1.y, fmaf(av.y, g1.w * g1.w, fmaf(av.z, g2.y * g2.y, fmaf(av.w, g2.w * g2.w, v4))));
    }
    for (int off = 32; off; off >>= 1) {
        v0 += __shfl_xor(v0, off, 64); v1 += __shfl_xor(v1, off, 64);
        v2 += __shfl_xor(v2, off, 64); v3 += __shfl_xor(v3, off, 64);
        v4 += __shfl_xor(v4, off, 64);
    }
    if ((t & 63) == 0) {
        int w = t >> 6;
        red[w][0] = v0; red[w][1] = v1; red[w][2] = v2; red[w][3] = v3; red[w][4] = v4;
    }
    __syncthreads();
    if (t == 0) {
        float A0 = red[0][0] + red[1][0] + red[2][0] + red[3][0];
        float A1x = red[0][1] + red[1][1] + red[2][1] + red[3][1];
        float A1y = red[0][2] + red[1][2] + red[2][2] + red[3][2];
        float A2x = red[0][3] + red[1][3] + red[2][3] + red[3][3];
        float A2y = red[0][4] + red[1][4] + red[2][4] + red[3][4];
        positions[bs * 2 + 0] = A1x;
        positions[bs * 2 + 1] = A1y;
        float sx = A2x - A1x * A1x * (2.f - A0);
        float sy = A2y - A1y * A1y * (2.f - A0);
        scales[bs * 2 + 0] = fminf(fmaxf(sqrtf(fmaxf(sx, 0.f)), 1e-3f), 2.f);
        scales[bs * 2 + 1] = fminf(fmaxf(sqrtf(fmaxf(sy, 0.f)), 1e-3f), 2.f);
        stats[bs] = A0;
    }
}

// ---------------------------------------------------------------- GRU + slot MLP
__global__ __launch_bounds__(64) void k_gru_mlp(
    const float* __restrict__ H, const float* __restrict__ stats,
    const float* __restrict__ W2, const float* __restrict__ b2,
    const float* __restrict__ W_ih, const float* __restrict__ W_hh,
    const float* __restrict__ b_ih, const float* __restrict__ b_hh,
    const float* __restrict__ lmg, const float* __restrict__ lmb,
    const float* __restrict__ W3, const float* __restrict__ b3,
    const float* __restrict__ W4, const float* __restrict__ b4,
    float* __restrict__ slots) {
    int bs = blockIdx.x;
    int c = threadIdx.x;
    __shared__ float hl[DHH], ul[DD], sl[DD], yl[DD], hml[DHH];
    hl[c] = H[bs * DHH + c];
    hl[c + 64] = H[bs * DHH + 64 + c];
    float hold = slots[bs * DD + c];
    sl[c] = hold;
    __syncthreads();
    float A0 = stats[bs];
    float u = A0 * b2[c];
    for (int o = 0; o < DHH; o += 4) {
        float4 w = *(const float4*)(W2 + c * DHH + o);
        u = fmaf(w.x, hl[o], fmaf(w.y, hl[o + 1], fmaf(w.z, hl[o + 2], fmaf(w.w, hl[o + 3], u))));
    }
    ul[c] = u;
    __syncthreads();
    float gir = b_ih[c], giz = b_ih[64 + c], gin = b_ih[128 + c];
    float ghr = b_hh[c], ghz = b_hh[64 + c], ghn = b_hh[128 + c];
    for (int k4 = 0; k4 < DD; k4 += 4) {
        float4 uu = *(const float4*)(ul + k4);
        float4 hh = *(const float4*)(sl + k4);
        gir += dot4(uu, *(const float4*)(W_ih + c * DD + k4));
        giz += dot4(uu, *(const float4*)(W_ih + (64 + c) * DD + k4));
        gin += dot4(uu, *(const float4*)(W_ih + (128 + c) * DD + k4));
        ghr += dot4(hh, *(const float4*)(W_hh + c * DD + k4));
        ghz += dot4(hh, *(const float4*)(W_hh + (64 + c) * DD + k4));
        ghn += dot4(hh, *(const float4*)(W_hh + (128 + c) * DD + k4));
    }
    float rg = 1.f / (1.f + expf(-(gir + ghr)));
    float zg = 1.f / (1.f + expf(-(giz + ghz)));
    float ng = tanhf(gin + rg * ghn);
    float snew = (1.f - zg) * ng + zg * hold;
    float sum = snew;
    for (int off = 32; off; off >>= 1) sum += __shfl_xor(sum, off, 64);
    float m = sum * (1.f / 64.f);
    float dv = snew - m;
    float vv = dv * dv;
    for (int off = 32; off; off >>= 1) vv += __shfl_xor(vv, off, 64);
    yl[c] = dv * rsqrtf(vv * (1.f / 64.f) + LN_EPS_F) * lmg[c] + lmb[c];
    __syncthreads();
    float h0 = b3[c], h1 = b3[64 + c];
    for (int k4 = 0; k4 < DD; k4 += 4) {
        float4 yy = *(const float4*)(yl + k4);
        h0 += dot4(yy, *(const float4*)(W3 + c * DD + k4));
        h1 += dot4(yy, *(const float4*)(W3 + (64 + c) * DD + k4));
    }
    hml[c] = fmaxf(h0, 0.f);
    hml[64 + c] = fmaxf(h1, 0.f);
    __syncthreads();
    float outv = b4[c];
    for (int o4 = 0; o4 < DHH; o4 += 4) {
        float4 hm4 = *(const float4*)(hml + o4);
        outv += dot4(hm4, *(const float4*)(W4 + c * DHH + o4));
    }
    slots[bs * DD + c] = outv;
}

// ---------------------------------------------------------------- write out
__global__ __launch_bounds__(256) void k_write_out(
    const float* __restrict__ slots, const float* __restrict__ positions,
    const float* __restrict__ scales, float* __restrict__ out) {
    int tid = blockIdx.x * 256 + threadIdx.x;
    if (tid >= BB * SS * 68) return;
    int bs = tid / 68, c = tid % 68;
    float v;
    if (c < 64) v = slots[bs * 64 + c];
    else if (c < 66) v = positions[bs * 2 + (c - 64)];
    else v = scales[bs * 2 + (c - 66)];
    out[tid] = v;
}

// ---------------------------------------------------------------- launcher
extern "C" void kernel_launch(void* const* d_in, const int* in_sizes, int n_in,
                              void* d_out, int out_size, void* d_ws, size_t ws_size,
                              hipStream_t stream) {
    (void)in_sizes; (void)n_in; (void)out_size; (void)ws_size;
    const float* inp = (const float*)d_in[0];
    const float* slots_in = (const float*)d_in[1];
    const float* Wq = (const float*)d_in[2];
    const float* Wk = (const float*)d_in[3];
    const float* Wv = (const float*)d_in[4];
    const float* Wg = (const float*)d_in[5];
    const float* bg = (const float*)d_in[6];
    const float* lpg = (const float*)d_in[7];
    const float* lpb = (const float*)d_in[8];
    const float* W1 = (const float*)d_in[9];
    const float* b1 = (const float*)d_in[10];
    const float* W2 = (const float*)d_in[11];
    const float* b2 = (const float*)d_in[12];
    const float* W_ih = (const float*)d_in[13];
    const float* W_hh = (const float*)d_in[14];
    const float* b_ih = (const float*)d_in[15];
    const float* b_hh = (const float*)d_in[16];
    const float* lmg = (const float*)d_in[17];
    const float* lmb = (const float*)d_in[18];
    const float* W3 = (const float*)d_in[19];
    const float* b3 = (const float*)d_in[20];
    const float* W4 = (const float*)d_in[21];
    const float* b4 = (const float*)d_in[22];
    const float* lsg = (const float*)d_in[23];
    const float* lsb = (const float*)d_in[24];
    float* out = (float*)d_out;
    float* ws = (float*)d_ws;

    const size_t NR = (size_t)BB * NN;
    size_t o_uk = 0;
    size_t o_uv = o_uk + NR * 128;
    size_t o_kaux = o_uv + NR * 128;
    size_t o_vaux = o_kaux + NR * 8;
    size_t o_gbuf = o_vaux + NR * 8;
    size_t o_dots = o_gbuf + NR * 2;
    size_t o_attn = o_dots + NR * SS;
    size_t o_slots = o_attn + NR * SS;
    size_t o_pos = o_slots + BB * SS * DD;
    size_t o_scl = o_pos + BB * SS * 2;
    size_t o_w2q = o_scl + BB * SS * 2;
    size_t o_qb2 = o_w2q + BB * SS * DHH;
    size_t o_Mv = o_qb2 + BB * SS;
    size_t o_Lv = o_Mv + BB * SS;
    size_t o_H = o_Lv + BB * SS;
    size_t o_stats = o_H + BB * SS * DHH;
    size_t o_W1p = o_stats + BB * SS;
    size_t o_avec = o_W1p + DHH * DD;
    size_t o_bvec = o_avec + DHH;
    size_t o_s1v = o_bvec + DHH;
    size_t o_b1p = o_s1v + DHH;
    size_t o_wgc = o_b1p + DHH;
    size_t o_Wall = o_wgc + 8;
    size_t o_cu = o_Wall + 2 * DHH * DD;

    float* uk = ws + o_uk;
    float* uv = ws + o_uv;
    float* kaux = ws + o_kaux;
    float* vaux = ws + o_vaux;
    float* gbuf = ws + o_gbuf;
    float* dots = ws + o_dots;
    float* attn = ws + o_attn;
    float* slots = ws + o_slots;
    float* positions = ws + o_pos;
    float* scales = ws + o_scl;
    float* w2q = ws + o_w2q;
    float* qb2 = ws + o_qb2;
    float* Mv = ws + o_Mv;
    float* Lv = ws + o_Lv;
    float* H = ws + o_H;
    float* stats = ws + o_stats;
    float* W1p = ws + o_W1p;
    float* avec = ws + o_avec;
    float* bvec = ws + o_bvec;
    float* s1v = ws + o_s1v;
    float* b1p = ws + o_b1p;
    float* wgc = ws + o_wgc;
    float* Wall = ws + o_Wall;
    float* cu = ws + o_cu;

    k_init_slots<<<32, 256, 0, stream>>>(slots_in, slots, positions, scales);
    k_prep_w<<<1, 256, 0, stream>>>(W1, lpg, lpb, b1, Wg, W1p, avec, bvec, s1v, b1p, wgc);
    k_prep_w2<<<64, 256, 0, stream>>>(W1p, Wk, Wv, bg, Wall, cu);
    k_prep_main<<<dim3(1024, 3), 256, 0, stream>>>(inp, Wall, cu, Wk, Wv, bg, Wg,
                                                   uk, uv, kaux, vaux, gbuf);

    for (int it = 0; it <= NITERS; ++it) {
        k_slot_prep<<<BB, 512, 0, stream>>>(slots, lsg, lsb, Wq, W2, b2, w2q, qb2);
        k_pass1<<<dim3(64, BB), 256, 0, stream>>>(uk, kaux, positions, scales,
                                                  avec, bvec, s1v, b1p, wgc, w2q, qb2, dots);
        k_softmax_ms<<<BB * SS, 256, 0, stream>>>(dots, Mv, Lv, H);
        k_attn<<<dim3(16, BB), 256, 0, stream>>>(dots, Mv, Lv, attn);
        if (it < NITERS) {
            k_pass2<<<dim3(64, BB), 256, 0, stream>>>(uv, vaux, positions, scales,
                                                      avec, bvec, s1v, b1p, wgc, attn, H);
            k_stats<<<BB * SS, 256, 0, stream>>>(attn, gbuf, positions, scales, stats);
            k_gru_mlp<<<BB * SS, 64, 0, stream>>>(H, stats, W2, b2, W_ih, W_hh, b_ih, b_hh,
                                                  lmg, lmb, W3, b3, W4, b4, slots);
        } else {
            k_stats<<<BB * SS, 256, 0, stream>>>(attn, gbuf, positions, scales, stats);
        }
    }
    k_write_out<<<34, 256, 0, stream>>>(slots, positions, scales, out);
}

// Round 11
// 455.130 us; speedup vs baseline: 1.2971x; 1.0315x over previous
//
#include <hip/hip_runtime.h>
#include <math.h>

#define BB 16
#define NN 4096
#define SS 8
#define DD 64
#define DHH 128
#define CIN 66
#define NITERS 3
#define LN_EPS_F 1e-5f
#define EPS_ATTN_F 1e-8f
#define QSCALE 0.125f    // d^-0.5
#define LO_SCALE 2048.0f
#define LO_INV 4.8828125e-4f

typedef __attribute__((ext_vector_type(8))) _Float16 half8;
typedef __attribute__((ext_vector_type(4))) float f32x4;
union H8 { half8 v; _Float16 u[8]; };

__device__ __forceinline__ float dot4(float4 a, float4 b) {
    return fmaf(a.x, b.x, fmaf(a.y, b.y, fmaf(a.z, b.z, a.w * b.w)));
}

__device__ __forceinline__ void split_fp16(float z, _Float16& h, _Float16& l) {
    _Float16 hh = (_Float16)z;
    float rem = (z - (float)hh) * LO_SCALE;
    h = hh;
    l = (_Float16)rem;
}

// ---------------------------------------------------------------- init slots
__global__ __launch_bounds__(256) void k_init_slots(
    const float* __restrict__ slots_in, float* __restrict__ slots,
    float* __restrict__ positions, float* __restrict__ scales) {
    int tid = blockIdx.x * 256 + threadIdx.x;
    if (tid < BB * SS * DD) {
        int s = (tid / DD) % SS;
        int c = tid % DD;
        slots[tid] = slots_in[s * 68 + c];
    }
    if (tid < BB * SS * 2) {
        int s = (tid >> 1) & 7;
        int p = tid & 1;
        float po = slots_in[s * 68 + 64 + p];
        positions[tid] = fminf(fmaxf(po, -1.f), 1.f);
        float sc = slots_in[s * 68 + 66 + p];
        scales[tid] = fminf(fmaxf(sc, 1e-3f), 2.f);
    }
}

// ---------------------------------------------------------------- prep W1-derived constants
__global__ __launch_bounds__(256) void k_prep_w(
    const float* __restrict__ W1, const float* __restrict__ lpg,
    const float* __restrict__ lpb, const float* __restrict__ b1,
    const float* __restrict__ Wg,
    float* __restrict__ W1p, float* __restrict__ avec, float* __restrict__ bvec,
    float* __restrict__ s1vec, float* __restrict__ b1p, float* __restrict__ wgc) {
    __shared__ float w1s[128 * 68];
    int tid = threadIdx.x;
    for (int q = 0; q < 8; q++) {
        int flat = q * 1024 + tid * 4;
        int o = flat >> 6, c = flat & 63;
        *(float4*)(w1s + o * 68 + c) = *(const float4*)(W1 + flat);
    }
    __syncthreads();
    if (tid < 128) {
        int o = tid;
        float a = 0.f, bv = 0.f, s1 = 0.f, b1a = b1[o];
        for (int c = 0; c < 64; c++) {
            float w0 = w1s[o * 68 + c];
            float w = w0 * lpg[c];
            W1p[o * 64 + c] = w;
            a = fmaf(w, Wg[2 * c], a);
            bv = fmaf(w, Wg[2 * c + 1], bv);
            s1 += w;
            b1a = fmaf(w0, lpb[c], b1a);
        }
        avec[o] = a; bvec[o] = bv; s1vec[o] = s1; b1p[o] = b1a;
    }
    if (tid == 128) {
        float mwA = 0.f, mwB = 0.f, AA = 0.f, BBv = 0.f, AB = 0.f;
        for (int c = 0; c < 64; c++) {
            float wa = Wg[2 * c], wb = Wg[2 * c + 1];
            mwA += wa; mwB += wb;
            AA = fmaf(wa, wa, AA); BBv = fmaf(wb, wb, BBv); AB = fmaf(wa, wb, AB);
        }
        wgc[0] = mwA * (1.f / 64.f);
        wgc[1] = mwB * (1.f / 64.f);
        wgc[2] = AA * (1.f / 64.f);
        wgc[3] = BBv * (1.f / 64.f);
        wgc[4] = AB * (2.f / 64.f);
    }
}

// ---------------------------------------------------------------- composite weights
__global__ __launch_bounds__(256) void k_prep_w2(
    const float* __restrict__ W1p, const float* __restrict__ Wk,
    const float* __restrict__ Wv, const float* __restrict__ bg,
    float* __restrict__ Wall, float* __restrict__ cu) {
    int flat = blockIdx.x * 256 + threadIdx.x;   // 64 blocks -> 16384
    int mat = flat >> 13, rem = flat & 8191;
    int o = rem >> 6, c = rem & 63;
    const float* Wm = mat ? Wv : Wk;
    float acc = 0.f;
    for (int d = 0; d < 64; d++)
        acc = fmaf(W1p[o * 64 + d], Wm[d * 64 + c], acc);
    Wall[flat] = acc;
    if (flat < 128) {
        float a = 0.f;
        for (int d = 0; d < 64; d++) a = fmaf(W1p[flat * 64 + d], bg[d], a);
        cu[flat] = a;
    }
}

// ---------------------------------------------------------------- W fragments (fp16 hi/lo)
// frag layout (verified r3): lane holds W[o=ot*16+(lane&15)][k=ks*32+(lane>>4)*8+j]
__global__ __launch_bounds__(256) void k_prep_frag(
    const float* __restrict__ Wall, const float* __restrict__ Wk,
    const float* __restrict__ Wv,
    _Float16* __restrict__ cwh, _Float16* __restrict__ cwl,
    _Float16* __restrict__ mwh, _Float16* __restrict__ mwl) {
    int idx = blockIdx.x * 256 + threadIdx.x;    // grid 12 -> 3072
    if (idx < 2048) {
        int f = idx >> 6, lane = idx & 63;       // f = m*16 + ot*2 + ks
        int m = f >> 4, rest = f & 15;
        int ot = rest >> 1, ks = rest & 1;
        int o = ot * 16 + (lane & 15);
        int k0 = ks * 32 + (lane >> 4) * 8;
        const float* src = Wall + m * 8192 + o * 64 + k0;
        #pragma unroll
        for (int j = 0; j < 8; j++) {
            _Float16 h, l;
            split_fp16(src[j], h, l);
            cwh[(size_t)f * 512 + lane * 8 + j] = h;
            cwl[(size_t)f * 512 + lane * 8 + j] = l;
        }
    } else if (idx < 3072) {
        int id2 = idx - 2048;
        int f = id2 >> 6, lane = id2 & 63;       // f = m*8 + ot*2 + ks
        int m = f >> 3, rest = f & 7;
        int ot = rest >> 1, ks = rest & 1;
        int o = ot * 16 + (lane & 15);
        int k0 = ks * 32 + (lane >> 4) * 8;
        const float* src = (m ? Wv : Wk) + o * 64 + k0;
        #pragma unroll
        for (int j = 0; j < 8; j++) {
            _Float16 h, l;
            split_fp16(src[j], h, l);
            mwh[(size_t)f * 512 + lane * 8 + j] = h;
            mwl[(size_t)f * 512 + lane * 8 + j] = l;
        }
    }
}

// ---------------------------------------------------------------- MFMA prep: uk/uv + moments
// grid (1024, 2), 256 thr, 64 rows/block; y=0: uk+kaux+gbuf, y=1: uv+vaux
__global__ __launch_bounds__(256) void k_prep_mfma(
    const float* __restrict__ inp,
    const _Float16* __restrict__ cwh, const _Float16* __restrict__ cwl,
    const _Float16* __restrict__ mwh, const _Float16* __restrict__ mwl,
    const float* __restrict__ cu, const float* __restrict__ bg,
    const float* __restrict__ Wg,
    float* __restrict__ uk, float* __restrict__ uv,
    float* __restrict__ kaux, float* __restrict__ vaux, float* __restrict__ gbuf) {
    __shared__ float T[4][16 * 132];
    int tid = threadIdx.x;
    int wv = tid >> 6, lane = tid & 63;
    int quad = lane >> 4, col = lane & 15;
    int mat = blockIdx.y;
    int rowTile = blockIdx.x * 64 + wv * 16;
    // A-frags from inp (rows 8-B aligned -> float2 loads)
    half8 ah[2], al[2];
    {
        int rA = rowTile + col;
        const float* rp = inp + (size_t)rA * CIN + quad * 8;
        #pragma unroll
        for (int ks = 0; ks < 2; ks++) {
            H8 h, l;
            #pragma unroll
            for (int q = 0; q < 4; q++) {
                float2 v = *(const float2*)(rp + ks * 32 + 2 * q);
                split_fp16(v.x, h.u[2 * q], l.u[2 * q]);
                split_fp16(v.y, h.u[2 * q + 1], l.u[2 * q + 1]);
            }
            ah[ks] = h.v; al[ks] = l.v;
        }
    }
    // composite GEMM -> T (per-wave region)
    const _Float16* cwhm = cwh + (size_t)mat * 16 * 512;
    const _Float16* cwlm = cwl + (size_t)mat * 16 * 512;
    #pragma unroll
    for (int ot = 0; ot < 8; ot++) {
        f32x4 acc1 = {0.f, 0.f, 0.f, 0.f}, acc2 = {0.f, 0.f, 0.f, 0.f};
        #pragma unroll
        for (int ks = 0; ks < 2; ks++) {
            half8 bh = *(const half8*)(cwhm + (size_t)(ot * 2 + ks) * 512 + lane * 8);
            half8 bl = *(const half8*)(cwlm + (size_t)(ot * 2 + ks) * 512 + lane * 8);
            acc1 = __builtin_amdgcn_mfma_f32_16x16x32_f16(ah[ks], bh, acc1, 0, 0, 0);
            acc2 = __builtin_amdgcn_mfma_f32_16x16x32_f16(al[ks], bh, acc2, 0, 0, 0);
            acc2 = __builtin_amdgcn_mfma_f32_16x16x32_f16(ah[ks], bl, acc2, 0, 0, 0);
        }
        float cuv = cu[ot * 16 + col];
        #pragma unroll
        for (int r = 0; r < 4; r++) {
            float u = fmaf(acc2[r], LO_INV, acc1[r]) + cuv;
            T[wv][(quad * 4 + r) * 132 + ot * 16 + col] = u;
        }
    }
    // moments GEMM (k or v): 4 ot-tiles, C-layout row=quad*4+r
    const _Float16* mwhm = mwh + (size_t)mat * 8 * 512;
    const _Float16* mwlm = mwl + (size_t)mat * 8 * 512;
    float mk[4] = {0.f, 0.f, 0.f, 0.f}, kk2[4] = {0.f, 0.f, 0.f, 0.f};
    float kA[4] = {0.f, 0.f, 0.f, 0.f}, kB[4] = {0.f, 0.f, 0.f, 0.f};
    #pragma unroll
    for (int ot = 0; ot < 4; ot++) {
        f32x4 acc1 = {0.f, 0.f, 0.f, 0.f}, acc2 = {0.f, 0.f, 0.f, 0.f};
        #pragma unroll
        for (int ks = 0; ks < 2; ks++) {
            half8 bh = *(const half8*)(mwhm + (size_t)(ot * 2 + ks) * 512 + lane * 8);
            half8 bl = *(const half8*)(mwlm + (size_t)(ot * 2 + ks) * 512 + lane * 8);
            acc1 = __builtin_amdgcn_mfma_f32_16x16x32_f16(ah[ks], bh, acc1, 0, 0, 0);
            acc2 = __builtin_amdgcn_mfma_f32_16x16x32_f16(al[ks], bh, acc2, 0, 0, 0);
            acc2 = __builtin_amdgcn_mfma_f32_16x16x32_f16(ah[ks], bl, acc2, 0, 0, 0);
        }
        int o = ot * 16 + col;
        float bgo = bg[o], wa = Wg[2 * o], wb = Wg[2 * o + 1];
        #pragma unroll
        for (int r = 0; r < 4; r++) {
            float x = fmaf(acc2[r], LO_INV, acc1[r]) + bgo;
            mk[r] += x; kk2[r] = fmaf(x, x, kk2[r]);
            kA[r] = fmaf(x, wa, kA[r]); kB[r] = fmaf(x, wb, kB[r]);
        }
    }
    #pragma unroll
    for (int off = 1; off <= 8; off <<= 1) {
        #pragma unroll
        for (int r = 0; r < 4; r++) {
            mk[r] += __shfl_xor(mk[r], off, 64);
            kk2[r] += __shfl_xor(kk2[r], off, 64);
            kA[r] += __shfl_xor(kA[r], off, 64);
            kB[r] += __shfl_xor(kB[r], off, 64);
        }
    }
    float* aux = mat ? vaux : kaux;
    if (col == 0) {
        #pragma unroll
        for (int r = 0; r < 4; r++) {
            int row = rowTile + quad * 4 + r;
            float2 g = *(const float2*)(inp + (size_t)row * CIN + 64);
            float4 m1 = {mk[r] * (1.f / 64.f), kk2[r] * (1.f / 64.f),
                         kA[r] * (1.f / 32.f), kB[r] * (1.f / 32.f)};
            float4 m2 = {g.x, g.y, 0.f, 0.f};
            *(float4*)(aux + (size_t)row * 8) = m1;
            *(float4*)(aux + (size_t)row * 8 + 4) = m2;
            if (mat == 0) {
                float2 gw = {g.x, g.y};
                *(float2*)(gbuf + (size_t)row * 2) = gw;
            }
        }
    }
    __syncthreads();
    // coalesced store: 4 lanes per row, 512 B contiguous per row
    {
        float* dst = mat ? uv : uk;
        int r = lane >> 2, cseg = (lane & 3) * 32;
        const float* Tr = &T[wv][r * 132 + cseg];
        float* gp = dst + (size_t)(rowTile + r) * 128 + cseg;
        #pragma unroll
        for (int q = 0; q < 8; q++)
            *(float4*)(gp + 4 * q) = *(const float4*)(Tr + 4 * q);
    }
}

// ---------------------------------------------------------------- slot_prep: w2q, qb2
__global__ __launch_bounds__(512) void k_slot_prep(
    const float* __restrict__ slots, const float* __restrict__ lsg,
    const float* __restrict__ lsb, const float* __restrict__ Wq,
    const float* __restrict__ W2, const float* __restrict__ b2,
    float* __restrict__ w2q, float* __restrict__ qb2) {
    __shared__ float sn[512];
    __shared__ float qv[SS][64];
    __shared__ float wsum[8], wsum2[8];
    int b = blockIdx.x, t = threadIdx.x;
    int s = t >> 6, c = t & 63;
    float x = slots[(b * SS + s) * DD + c];
    float sum = x;
    for (int off = 32; off; off >>= 1) sum += __shfl_xor(sum, off, 64);
    float m = sum * (1.f / 64.f);
    float dv = x - m;
    float vs = dv * dv;
    for (int off = 32; off; off >>= 1) vs += __shfl_xor(vs, off, 64);
    float y = dv * rsqrtf(vs * (1.f / 64.f) + LN_EPS_F) * lsg[c] + lsb[c];
    float s1 = y, s2 = y * y;
    for (int off = 32; off; off >>= 1) { s1 += __shfl_xor(s1, off, 64); s2 += __shfl_xor(s2, off, 64); }
    if (c == 0) { wsum[s] = s1; wsum2[s] = s2; }
    __syncthreads();
    float ts1 = 0.f, ts2 = 0.f;
    #pragma unroll
    for (int i = 0; i < 8; i++) { ts1 += wsum[i]; ts2 += wsum2[i]; }
    float gm = ts1 * (1.f / 512.f);
    float gv = ts2 * (1.f / 512.f) - gm * gm;
    sn[t] = (y - gm) * rsqrtf(gv + LN_EPS_F);
    __syncthreads();
    float acc = 0.f;
    for (int j4 = 0; j4 < 64; j4 += 4)
        acc += dot4(*(const float4*)&sn[s * 64 + j4], *(const float4*)(Wq + c * 64 + j4));
    qv[s][c] = acc;
    __syncthreads();
    float a0 = 0.f, a1 = 0.f;
    for (int cc = 0; cc < 64; cc++) {
        float qc = qv[s][cc];
        a0 = fmaf(qc, W2[cc * DHH + c], a0);
        a1 = fmaf(qc, W2[cc * DHH + c + 64], a1);
    }
    w2q[(b * SS + s) * DHH + c] = a0 * QSCALE;
    w2q[(b * SS + s) * DHH + c + 64] = a1 * QSCALE;
    float qb = qv[s][c] * b2[c];
    for (int off = 32; off; off >>= 1) qb += __shfl_xor(qb, off, 64);
    if (c == 0) qb2[b * SS + s] = qb * QSCALE;
}

// ---------------------------------------------------------------- pass1: dots (round-5)
__global__ __launch_bounds__(256) void k_pass1(
    const float* __restrict__ uk, const float* __restrict__ kaux,
    const float* __restrict__ positions, const float* __restrict__ scales,
    const float* __restrict__ avec, const float* __restrict__ bvec,
    const float* __restrict__ s1vec, const float* __restrict__ b1p,
    const float* __restrict__ wgc, const float* __restrict__ w2q,
    const float* __restrict__ qb2, float* __restrict__ dots) {
    int tid = threadIdx.x;
    int chunk = blockIdx.x, b = blockIdx.y;
    int wv = tid >> 6, lane = tid & 63, rh = lane >> 5, ol = lane & 31;
    int o4 = ol * 4;
    float4 a4 = *(const float4*)(avec + o4);
    float4 bv4 = *(const float4*)(bvec + o4);
    float4 s14 = *(const float4*)(s1vec + o4);
    float4 b14 = *(const float4*)(b1p + o4);
    float mwA = wgc[0], mwB = wgc[1], AA = wgc[2], BBc = wgc[3], AB2 = wgc[4];
    float p0[8], p1[8], rc0[8], rc1[8], qb[8];
    float4 wq[8];
    #pragma unroll
    for (int s = 0; s < 8; s++) {
        int bs = b * 8 + s;
        p0[s] = positions[bs * 2]; p1[s] = positions[bs * 2 + 1];
        rc0[s] = 1.f / scales[bs * 2]; rc1[s] = 1.f / scales[bs * 2 + 1];
        qb[s] = qb2[bs];
        wq[s] = *(const float4*)(w2q + (size_t)bs * DHH + o4);
    }
    int row0 = chunk * 64 + wv * 16 + rh;
    size_t rg = (size_t)b * NN + row0;
    float4 m1 = *(const float4*)(kaux + rg * 8);
    float4 m2 = *(const float4*)(kaux + rg * 8 + 4);
    float4 u4 = *(const float4*)(uk + rg * 128 + o4);
    for (int st = 0; st < 8; st++) {
        float4 n1, n2, nu;
        if (st < 7) {
            size_t rgn = rg + (size_t)(st + 1) * 2;
            n1 = *(const float4*)(kaux + rgn * 8);
            n2 = *(const float4*)(kaux + rgn * 8 + 4);
            nu = *(const float4*)(uk + rgn * 128 + o4);
        }
        int row = row0 + st * 2;
        #pragma unroll
        for (int s = 0; s < 8; s++) {
            float rel0 = (m2.x - p0[s]) * rc0[s];
            float rel1 = (m2.y - p1[s]) * rc1[s];
            float m = fmaf(rel1, mwB, fmaf(rel0, mwA, m1.x));
            float q2 = fmaf(rel0, fmaf(rel0, AA, m1.z), m1.y);
            q2 = fmaf(rel1, fmaf(rel1, BBc, m1.w), q2);
            q2 = fmaf(rel0 * rel1, AB2, q2);
            float var = fmaf(-m, m, q2);
            float rstd = rsqrtf(fmaxf(var, 0.f) + LN_EPS_F);
            float p = 0.f, t, h;
            t = fmaf(-m, s14.x, u4.x); t = fmaf(rel0, a4.x, t); t = fmaf(rel1, bv4.x, t);
            h = fmaf(rstd, t, b14.x); p = fmaf(fmaxf(h, 0.f), wq[s].x, p);
            t = fmaf(-m, s14.y, u4.y); t = fmaf(rel0, a4.y, t); t = fmaf(rel1, bv4.y, t);
            h = fmaf(rstd, t, b14.y); p = fmaf(fmaxf(h, 0.f), wq[s].y, p);
            t = fmaf(-m, s14.z, u4.z); t = fmaf(rel0, a4.z, t); t = fmaf(rel1, bv4.z, t);
            h = fmaf(rstd, t, b14.z); p = fmaf(fmaxf(h, 0.f), wq[s].z, p);
            t = fmaf(-m, s14.w, u4.w); t = fmaf(rel0, a4.w, t); t = fmaf(rel1, bv4.w, t);
            h = fmaf(rstd, t, b14.w); p = fmaf(fmaxf(h, 0.f), wq[s].w, p);
            p += __shfl_xor(p, 1, 64);
            p += __shfl_xor(p, 2, 64);
            p += __shfl_xor(p, 4, 64);
            p += __shfl_xor(p, 8, 64);
            p += __shfl_xor(p, 16, 64);
            if (ol == 0)
                dots[(size_t)(b * 8 + s) * NN + row] = p + qb[s];
        }
        m1 = n1; m2 = n2; u4 = nu;
    }
}

// ---------------------------------------------------------------- pass2: H (round-5)
__global__ __launch_bounds__(256) void k_pass2(
    const float* __restrict__ uv, const float* __restrict__ vaux,
    const float* __restrict__ positions, const float* __restrict__ scales,
    const float* __restrict__ avec, const float* __restrict__ bvec,
    const float* __restrict__ s1vec, const float* __restrict__ b1p,
    const float* __restrict__ wgc, const float* __restrict__ attn,
    float* __restrict__ H) {
    __shared__ float Hw[4 * 1024];
    int tid = threadIdx.x;
    int chunk = blockIdx.x, b = blockIdx.y;
    int wv = tid >> 6, lane = tid & 63, rh = lane >> 5, ol = lane & 31;
    int o4 = ol * 4;
    float4 a4 = *(const float4*)(avec + o4);
    float4 bv4 = *(const float4*)(bvec + o4);
    float4 s14 = *(const float4*)(s1vec + o4);
    float4 b14 = *(const float4*)(b1p + o4);
    float mwA = wgc[0], mwB = wgc[1], AA = wgc[2], BBc = wgc[3], AB2 = wgc[4];
    float p0[8], p1[8], rc0[8], rc1[8];
    #pragma unroll
    for (int s = 0; s < 8; s++) {
        int bs = b * 8 + s;
        p0[s] = positions[bs * 2]; p1[s] = positions[bs * 2 + 1];
        rc0[s] = 1.f / scales[bs * 2]; rc1[s] = 1.f / scales[bs * 2 + 1];
    }
    float hq[8][4];
    #pragma unroll
    for (int s = 0; s < 8; s++)
        #pragma unroll
        for (int c = 0; c < 4; c++) hq[s][c] = 0.f;
    int row0 = chunk * 64 + wv * 16 + rh;
    size_t rg = (size_t)b * NN + row0;
    float4 m1 = *(const float4*)(vaux + rg * 8);
    float4 m2 = *(const float4*)(vaux + rg * 8 + 4);
    float4 u4 = *(const float4*)(uv + rg * 128 + o4);
    for (int st = 0; st < 8; st++) {
        float4 n1, n2, nu;
        if (st < 7) {
            size_t rgn = rg + (size_t)(st + 1) * 2;
            n1 = *(const float4*)(vaux + rgn * 8);
            n2 = *(const float4*)(vaux + rgn * 8 + 4);
            nu = *(const float4*)(uv + rgn * 128 + o4);
        }
        int row = row0 + st * 2;
        #pragma unroll
        for (int s = 0; s < 8; s++) {
            float ar = attn[(size_t)(b * 8 + s) * NN + row];
            float rel0 = (m2.x - p0[s]) * rc0[s];
            float rel1 = (m2.y - p1[s]) * rc1[s];
            float m = fmaf(rel1, mwB, fmaf(rel0, mwA, m1.x));
            float q2 = fmaf(rel0, fmaf(rel0, AA, m1.z), m1.y);
            q2 = fmaf(rel1, fmaf(rel1, BBc, m1.w), q2);
            q2 = fmaf(rel0 * rel1, AB2, q2);
            float var = fmaf(-m, m, q2);
            float rstd = rsqrtf(fmaxf(var, 0.f) + LN_EPS_F);
            float t, h;
            t = fmaf(-m, s14.x, u4.x); t = fmaf(rel0, a4.x, t); t = fmaf(rel1, bv4.x, t);
            h = fmaf(rstd, t, b14.x); hq[s][0] = fmaf(ar, fmaxf(h, 0.f), hq[s][0]);
            t = fmaf(-m, s14.y, u4.y); t = fmaf(rel0, a4.y, t); t = fmaf(rel1, bv4.y, t);
            h = fmaf(rstd, t, b14.y); hq[s][1] = fmaf(ar, fmaxf(h, 0.f), hq[s][1]);
            t = fmaf(-m, s14.z, u4.z); t = fmaf(rel0, a4.z, t); t = fmaf(rel1, bv4.z, t);
            h = fmaf(rstd, t, b14.z); hq[s][2] = fmaf(ar, fmaxf(h, 0.f), hq[s][2]);
            t = fmaf(-m, s14.w, u4.w); t = fmaf(rel0, a4.w, t); t = fmaf(rel1, bv4.w, t);
            h = fmaf(rstd, t, b14.w); hq[s][3] = fmaf(ar, fmaxf(h, 0.f), hq[s][3]);
        }
        m1 = n1; m2 = n2; u4 = nu;
    }
    #pragma unroll
    for (int s = 0; s < 8; s++)
        #pragma unroll
        for (int c = 0; c < 4; c++)
            hq[s][c] += __shfl_xor(hq[s][c], 32, 64);
    if (lane < 32) {
        #pragma unroll
        for (int s = 0; s < 8; s++) {
            float4 st = {hq[s][0], hq[s][1], hq[s][2], hq[s][3]};
            *(float4*)(Hw + wv * 1024 + s * 128 + o4) = st;
        }
    }
    __syncthreads();
    #pragma unroll
    for (int q = 0; q < 4; q++) {
        int flat = q * 256 + tid;
        float sum = Hw[flat] + Hw[1024 + flat] + Hw[2048 + flat] + Hw[3072 + flat];
        atomicAdd(&H[(size_t)b * 8 * DHH + flat], sum);
    }
}

// ---------------------------------------------------------------- softmax M,L (+zero H)
__global__ __launch_bounds__(256) void k_softmax_ms(
    const float* __restrict__ dots, float* __restrict__ Mv, float* __restrict__ Lv,
    float* __restrict__ H) {
    __shared__ float red[4];
    int bs = blockIdx.x, t = threadIdx.x;
    if (t < 128) H[(size_t)bs * DHH + t] = 0.f;
    const float* dp = dots + (size_t)bs * NN;
    float mx = -1e30f;
    #pragma unroll
    for (int it = 0; it < 4; it++) {
        float4 d = *(const float4*)(dp + it * 1024 + t * 4);
        mx = fmaxf(mx, fmaxf(fmaxf(d.x, d.y), fmaxf(d.z, d.w)));
    }
    for (int off = 32; off; off >>= 1) mx = fmaxf(mx, __shfl_xor(mx, off, 64));
    if ((t & 63) == 0) red[t >> 6] = mx;
    __syncthreads();
    float M = fmaxf(fmaxf(red[0], red[1]), fmaxf(red[2], red[3]));
    __syncthreads();
    float sm = 0.f;
    #pragma unroll
    for (int it = 0; it < 4; it++) {
        float4 d = *(const float4*)(dp + it * 1024 + t * 4);
        sm += expf(d.x - M) + expf(d.y - M) + expf(d.z - M) + expf(d.w - M);
    }
    for (int off = 32; off; off >>= 1) sm += __shfl_xor(sm, off, 64);
    if ((t & 63) == 0) red[t >> 6] = sm;
    __syncthreads();
    if (t == 0) { Mv[bs] = M; Lv[bs] = red[0] + red[1] + red[2] + red[3]; }
}

// ---------------------------------------------------------------- attn normalize
__global__ __launch_bounds__(256) void k_attn(
    const float* __restrict__ dots, const float* __restrict__ Mv,
    const float* __restrict__ Lv, float* __restrict__ attn) {
    int chunk = blockIdx.x, b = blockIdx.y;
    int n = chunk * 256 + threadIdx.x;
    float a[8];
    float rs = 0.f;
    #pragma unroll
    for (int s = 0; s < 8; s++) {
        int bs = b * 8 + s;
        float d = dots[(size_t)bs * NN + n];
        a[s] = expf(d - Mv[bs]) * (1.f / Lv[bs]) + EPS_ATTN_F;
        rs += a[s];
    }
    float inv = 1.f / rs;
    #pragma unroll
    for (int s = 0; s < 8; s++)
        attn[(size_t)(b * 8 + s) * NN + n] = a[s] * inv;
}

// ---------------------------------------------------------------- stats + finalize
__global__ __launch_bounds__(256) void k_stats(
    const float* __restrict__ attn, const float* __restrict__ gbuf,
    float* __restrict__ positions, float* __restrict__ scales,
    float* __restrict__ stats) {
    __shared__ float red[4][5];
    int bs = blockIdx.x, b = bs >> 3, t = threadIdx.x;
    const float* ap = attn + (size_t)bs * NN;
    const float* gb = gbuf + (size_t)b * NN * 2;
    float v0 = 0.f, v1 = 0.f, v2 = 0.f, v3 = 0.f, v4 = 0.f;
    #pragma unroll
    for (int it = 0; it < 4; it++) {
        int n0 = it * 1024 + t * 4;
        float4 av = *(const float4*)(ap + n0);
        float4 g1 = *(const float4*)(gb + (size_t)n0 * 2);
        float4 g2 = *(const float4*)(gb + (size_t)n0 * 2 + 4);
        v0 += av.x + av.y + av.z + av.w;
        v1 = fmaf(av.x, g1.x, fmaf(av.y, g1.z, fmaf(av.z, g2.x, fmaf(av.w, g2.z, v1))));
        v2 = fmaf(av.x, g1.y, fmaf(av.y, g1.w, fmaf(av.z, g2.y, fmaf(av.w, g2.w, v2))));
        v3 = fmaf(av.x, g1.x * g1.x, fmaf(av.y, g1.z * g1.z, fmaf(av.z, g2.x * g2.x, fmaf(av.w, g2.z * g2.z, v3))));
        v4 = fmaf(av.x, g1.y * g1.y, fmaf(av.y, g1.w * g1.w, fmaf(av.z, g2.y * g2.y, fmaf(av.w, g2.w * g2.w, v4))));
    }
    for (int off = 32; off; off >>= 1) {
        v0 += __shfl_xor(v0, off, 64); v1 += __shfl_xor(v1, off, 64);
        v2 += __shfl_xor(v2, off, 64); v3 += __shfl_xor(v3, off, 64);
        v4 += __shfl_xor(v4, off, 64);
    }
    if ((t & 63) == 0) {
        int w = t >> 6;
        red[w][0] = v0; red[w][1] = v1; red[w][2] = v2; red[w][3] = v3; red[w][4] = v4;
    }
    __syncthreads();
    if (t == 0) {
        float A0 = red[0][0] + red[1][0] + red[2][0] + red[3][0];
        float A1x = red[0][1] + red[1][1] + red[2][1] + red[3][1];
        float A1y = red[0][2] + red[1][2] + red[2][2] + red[3][2];
        float A2x = red[0][3] + red[1][3] + red[2][3] + red[3][3];
        float A2y = red[0][4] + red[1][4] + red[2][4] + red[3][4];
        positions[bs * 2 + 0] = A1x;
        positions[bs * 2 + 1] = A1y;
        float sx = A2x - A1x * A1x * (2.f - A0);
        float sy = A2y - A1y * A1y * (2.f - A0);
        scales[bs * 2 + 0] = fminf(fmaxf(sqrtf(fmaxf(sx, 0.f)), 1e-3f), 2.f);
        scales[bs * 2 + 1] = fminf(fmaxf(sqrtf(fmaxf(sy, 0.f)), 1e-3f), 2.f);
        stats[bs] = A0;
    }
}

// ---------------------------------------------------------------- GRU + slot MLP
__global__ __launch_bounds__(64) void k_gru_mlp(
    const float* __restrict__ H, const float* __restrict__ stats,
    const float* __restrict__ W2, const float* __restrict__ b2,
    const float* __restrict__ W_ih, const float* __restrict__ W_hh,
    const float* __restrict__ b_ih, const float* __restrict__ b_hh,
    const float* __restrict__ lmg, const float* __restrict__ lmb,
    const float* __restrict__ W3, const float* __restrict__ b3,
    const float* __restrict__ W4, const float* __restrict__ b4,
    float* __restrict__ slots) {
    int bs = blockIdx.x;
    int c = threadIdx.x;
    __shared__ float hl[DHH], ul[DD], sl[DD], yl[DD], hml[DHH];
    hl[c] = H[bs * DHH + c];
    hl[c + 64] = H[bs * DHH + 64 + c];
    float hold = slots[bs * DD + c];
    sl[c] = hold;
    __syncthreads();
    float A0 = stats[bs];
    float u = A0 * b2[c];
    for (int o = 0; o < DHH; o += 4) {
        float4 w = *(const float4*)(W2 + c * DHH + o);
        u = fmaf(w.x, hl[o], fmaf(w.y, hl[o + 1], fmaf(w.z, hl[o + 2], fmaf(w.w, hl[o + 3], u))));
    }
    ul[c] = u;
    __syncthreads();
    float gir = b_ih[c], giz = b_ih[64 + c], gin = b_ih[128 + c];
    float ghr = b_hh[c], ghz = b_hh[64 + c], ghn = b_hh[128 + c];
    for (int k4 = 0; k4 < DD; k4 += 4) {
        float4 uu = *(const float4*)(ul + k4);
        float4 hh = *(const float4*)(sl + k4);
        gir += dot4(uu, *(const float4*)(W_ih + c * DD + k4));
        giz += dot4(uu, *(const float4*)(W_ih + (64 + c) * DD + k4));
        gin += dot4(uu, *(const float4*)(W_ih + (128 + c) * DD + k4));
        ghr += dot4(hh, *(const float4*)(W_hh + c * DD + k4));
        ghz += dot4(hh, *(const float4*)(W_hh + (64 + c) * DD + k4));
        ghn += dot4(hh, *(const float4*)(W_hh + (128 + c) * DD + k4));
    }
    float rg = 1.f / (1.f + expf(-(gir + ghr)));
    float zg = 1.f / (1.f + expf(-(giz + ghz)));
    float ng = tanhf(gin + rg * ghn);
    float snew = (1.f - zg) * ng + zg * hold;
    float sum = snew;
    for (int off = 32; off; off >>= 1) sum += __shfl_xor(sum, off, 64);
    float m = sum * (1.f / 64.f);
    float dv = snew - m;
    float vv = dv * dv;
    for (int off = 32; off; off >>= 1) vv += __shfl_xor(vv, off, 64);
    yl[c] = dv * rsqrtf(vv * (1.f / 64.f) + LN_EPS_F) * lmg[c] + lmb[c];
    __syncthreads();
    float h0 = b3[c], h1 = b3[64 + c];
    for (int k4 = 0; k4 < DD; k4 += 4) {
        float4 yy = *(const float4*)(yl + k4);
        h0 += dot4(yy, *(const float4*)(W3 + c * DD + k4));
        h1 += dot4(yy, *(const float4*)(W3 + (64 + c) * DD + k4));
    }
    hml[c] = fmaxf(h0, 0.f);
    hml[64 + c] = fmaxf(h1, 0.f);
    __syncthreads();
    float outv = b4[c];
    for (int o4 = 0; o4 < DHH; o4 += 4) {
        float4 hm4 = *(const float4*)(hml + o4);
        outv += dot4(hm4, *(const float4*)(W4 + c * DHH + o4));
    }
    slots[bs * DD + c] = outv;
}

// ---------------------------------------------------------------- write out
__global__ __launch_bounds__(256) void k_write_out(
    const float* __restrict__ slots, const float* __restrict__ positions,
    const float* __restrict__ scales, float* __restrict__ out) {
    int tid = blockIdx.x * 256 + threadIdx.x;
    if (tid >= BB * SS * 68) return;
    int bs = tid / 68, c = tid % 68;
    float v;
    if (c < 64) v = slots[bs * 64 + c];
    else if (c < 66) v = positions[bs * 2 + (c - 64)];
    else v = scales[bs * 2 + (c - 66)];
    out[tid] = v;
}

// ---------------------------------------------------------------- launcher
extern "C" void kernel_launch(void* const* d_in, const int* in_sizes, int n_in,
                              void* d_out, int out_size, void* d_ws, size_t ws_size,
                              hipStream_t stream) {
    (void)in_sizes; (void)n_in; (void)out_size; (void)ws_size;
    const float* inp = (const float*)d_in[0];
    const float* slots_in = (const float*)d_in[1];
    const float* Wq = (const float*)d_in[2];
    const float* Wk = (const float*)d_in[3];
    const float* Wv = (const float*)d_in[4];
    const float* Wg = (const float*)d_in[5];
    const float* bg = (const float*)d_in[6];
    const float* lpg = (const float*)d_in[7];
    const float* lpb = (const float*)d_in[8];
    const float* W1 = (const float*)d_in[9];
    const float* b1 = (const float*)d_in[10];
    const float* W2 = (const float*)d_in[11];
    const float* b2 = (const float*)d_in[12];
    const float* W_ih = (const float*)d_in[13];
    const float* W_hh = (const float*)d_in[14];
    const float* b_ih = (const float*)d_in[15];
    const float* b_hh = (const float*)d_in[16];
    const float* lmg = (const float*)d_in[17];
    const float* lmb = (const float*)d_in[18];
    const float* W3 = (const float*)d_in[19];
    const float* b3 = (const float*)d_in[20];
    const float* W4 = (const float*)d_in[21];
    const float* b4 = (const float*)d_in[22];
    const float* lsg = (const float*)d_in[23];
    const float* lsb = (const float*)d_in[24];
    float* out = (float*)d_out;
    float* ws = (float*)d_ws;

    const size_t NR = (size_t)BB * NN;
    size_t o_uk = 0;
    size_t o_uv = o_uk + NR * 128;
    size_t o_kaux = o_uv + NR * 128;
    size_t o_vaux = o_kaux + NR * 8;
    size_t o_gbuf = o_vaux + NR * 8;
    size_t o_dots = o_gbuf + NR * 2;
    size_t o_attn = o_dots + NR * SS;
    size_t o_slots = o_attn + NR * SS;
    size_t o_pos = o_slots + BB * SS * DD;
    size_t o_scl = o_pos + BB * SS * 2;
    size_t o_w2q = o_scl + BB * SS * 2;
    size_t o_qb2 = o_w2q + BB * SS * DHH;
    size_t o_Mv = o_qb2 + BB * SS;
    size_t o_Lv = o_Mv + BB * SS;
    size_t o_H = o_Lv + BB * SS;
    size_t o_stats = o_H + BB * SS * DHH;
    size_t o_W1p = o_stats + BB * SS;
    size_t o_avec = o_W1p + DHH * DD;
    size_t o_bvec = o_avec + DHH;
    size_t o_s1v = o_bvec + DHH;
    size_t o_b1p = o_s1v + DHH;
    size_t o_wgc = o_b1p + DHH;
    size_t o_Wall = o_wgc + 8;
    size_t o_cu = o_Wall + 2 * DHH * DD;
    size_t o_cwh = o_cu + DHH;            // 2*16*512 halfs = 8192 floats
    size_t o_cwl = o_cwh + 8192;
    size_t o_mwh = o_cwl + 8192;          // 2*8*512 halfs = 4096 floats
    size_t o_mwl = o_mwh + 4096;

    float* uk = ws + o_uk;
    float* uv = ws + o_uv;
    float* kaux = ws + o_kaux;
    float* vaux = ws + o_vaux;
    float* gbuf = ws + o_gbuf;
    float* dots = ws + o_dots;
    float* attn = ws + o_attn;
    float* slots = ws + o_slots;
    float* positions = ws + o_pos;
    float* scales = ws + o_scl;
    float* w2q = ws + o_w2q;
    float* qb2 = ws + o_qb2;
    float* Mv = ws + o_Mv;
    float* Lv = ws + o_Lv;
    float* H = ws + o_H;
    float* stats = ws + o_stats;
    float* W1p = ws + o_W1p;
    float* avec = ws + o_avec;
    float* bvec = ws + o_bvec;
    float* s1v = ws + o_s1v;
    float* b1p = ws + o_b1p;
    float* wgc = ws + o_wgc;
    float* Wall = ws + o_Wall;
    float* cu = ws + o_cu;
    _Float16* cwh = (_Float16*)(ws + o_cwh);
    _Float16* cwl = (_Float16*)(ws + o_cwl);
    _Float16* mwh = (_Float16*)(ws + o_mwh);
    _Float16* mwl = (_Float16*)(ws + o_mwl);

    k_init_slots<<<32, 256, 0, stream>>>(slots_in, slots, positions, scales);
    k_prep_w<<<1, 256, 0, stream>>>(W1, lpg, lpb, b1, Wg, W1p, avec, bvec, s1v, b1p, wgc);
    k_prep_w2<<<64, 256, 0, stream>>>(W1p, Wk, Wv, bg, Wall, cu);
    k_prep_frag<<<12, 256, 0, stream>>>(Wall, Wk, Wv, cwh, cwl, mwh, mwl);
    k_prep_mfma<<<dim3(1024, 2), 256, 0, stream>>>(inp, cwh, cwl, mwh, mwl,
                                                   cu, bg, Wg, uk, uv, kaux, vaux, gbuf);

    for (int it = 0; it <= NITERS; ++it) {
        k_slot_prep<<<BB, 512, 0, stream>>>(slots, lsg, lsb, Wq, W2, b2, w2q, qb2);
        k_pass1<<<dim3(64, BB), 256, 0, stream>>>(uk, kaux, positions, scales,
                                                  avec, bvec, s1v, b1p, wgc, w2q, qb2, dots);
        k_softmax_ms<<<BB * SS, 256, 0, stream>>>(dots, Mv, Lv, H);
        k_attn<<<dim3(16, BB), 256, 0, stream>>>(dots, Mv, Lv, attn);
        if (it < NITERS) {
            k_pass2<<<dim3(64, BB), 256, 0, stream>>>(uv, vaux, positions, scales,
                                                      avec, bvec, s1v, b1p, wgc, attn, H);
            k_stats<<<BB * SS, 256, 0, stream>>>(attn, gbuf, positions, scales, stats);
            k_gru_mlp<<<BB * SS, 64, 0, stream>>>(H, stats, W2, b2, W_ih, W_hh, b_ih, b_hh,
                                                  lmg, lmb, W3, b3, W4, b4, slots);
        } else {
            k_stats<<<BB * SS, 256, 0, stream>>>(attn, gbuf, positions, scales, stats);
        }
    }
    k_write_out<<<34, 256, 0, stream>>>(slots, positions, scales, out);
}